// Round 16
// baseline (614.657 us; speedup 1.0000x reference)
//
#include <hip/hip_runtime.h>
#include <hip/hip_cooperative_groups.h>

namespace cg = cooperative_groups;

#define NN 10242

typedef short s8v __attribute__((ext_vector_type(8)));
typedef unsigned int u32x2 __attribute__((ext_vector_type(2)));
typedef float f32x4 __attribute__((ext_vector_type(4)));

static __device__ __forceinline__ float bf2f(unsigned short u) {
    unsigned int i = ((unsigned int)u) << 16;
    return __builtin_bit_cast(float, i);
}
static __device__ __forceinline__ float bfu32lo(unsigned int d) {
    return __builtin_bit_cast(float, d << 16);
}
static __device__ __forceinline__ float bfu32hi(unsigned int d) {
    return __builtin_bit_cast(float, d & 0xffff0000u);
}
static __device__ __forceinline__ unsigned short f2bf(float f) {
    unsigned int i = __builtin_bit_cast(unsigned int, f);
    unsigned int lsb = (i >> 16) & 1u;
    i += 0x7fffu + lsb;
    return (unsigned short)(i >> 16);
}
static __device__ __forceinline__ unsigned int cvtpk(float lo, float hi) {
    unsigned int r;
    asm("v_cvt_pk_bf16_f32 %0, %1, %2" : "=v"(r) : "v"(lo), "v"(hi));
    return r;
}
static __device__ __forceinline__ void gl_lds16(const unsigned short* g, unsigned short* l) {
    __builtin_amdgcn_global_load_lds(
        (const __attribute__((address_space(1))) unsigned int*)g,
        (__attribute__((address_space(3))) unsigned int*)l, 16, 0, 0);
}
template<int N> static __device__ __forceinline__ void waitv() {
    asm volatile("s_waitcnt vmcnt(%0)" :: "n"(N) : "memory");
    __builtin_amdgcn_sched_barrier(0);
}
static __device__ __forceinline__ void lgkm0() {
    asm volatile("s_waitcnt lgkmcnt(0)" ::: "memory");
    __builtin_amdgcn_sched_barrier(0);
}
static __device__ __forceinline__ int imin(int a, int b) { return a < b ? a : b; }

// ---- dtype detector ----
__global__ void detect_k(const void* __restrict__ wgt, int* __restrict__ flag) {
    const float* wf = (const float*)wgt;
    const int r = threadIdx.x;
    float s = wf[3 * r] + wf[3 * r + 1] + wf[3 * r + 2];
    bool ok = (s == s) && (fabsf(s - 1.f) < 0.05f);
    unsigned long long m = __ballot(ok);
    if (r == 0) *flag = (__popcll(m) >= 60) ? 1 : 0;
}

// ---- canonicalizer ----
struct Seg { const void* src; void* dst; int n; int nsrc; int mode; int K; int cout; int cpad; };
struct Tab { Seg s[16]; };

__global__ __launch_bounds__(256) void canon_k(Tab t, const int* __restrict__ flag) {
    const Seg sg = t.s[blockIdx.y];
    const bool f32src = (*flag != 0);
    for (int i = blockIdx.x * 256 + threadIdx.x; i < sg.n; i += gridDim.x * 256) {
        if (sg.mode == 0) {
            unsigned short v = 0;
            if (i < sg.nsrc)
                v = f32src ? f2bf(((const float*)sg.src)[i])
                           : ((const unsigned short*)sg.src)[i];
            ((unsigned short*)sg.dst)[i] = v;
        } else if (sg.mode == 1) {
            float v = f32src ? ((const float*)sg.src)[i]
                             : bf2f(((const unsigned short*)sg.src)[i]);
            ((float*)sg.dst)[i] = v;
        } else if (sg.mode == 2) {
            const int row = i / 80, col = i - row * 80;
            unsigned short v = 0;
            if (col < 75) {
                const int j = row * 75 + col;
                v = f32src ? f2bf(((const float*)sg.src)[j])
                           : ((const unsigned short*)sg.src)[j];
            }
            ((unsigned short*)sg.dst)[i] = v;
        } else if (sg.mode == 3) {
            const int e = i & 7;
            const int r = i >> 3;
            const int c = r % sg.cpad;
            const int k8 = r / sg.cpad;
            unsigned short v = 0;
            if (c < sg.cout) {
                const int j = c * sg.K + k8 * 8 + e;
                v = f32src ? f2bf(((const float*)sg.src)[j])
                           : ((const unsigned short*)sg.src)[j];
            }
            ((unsigned short*)sg.dst)[i] = v;
        } else {
            const int row = i >> 2, col = i & 3;
            unsigned short v = 0;
            if (col < 3) {
                const int j = row * 3 + col;
                v = f32src ? f2bf(((const float*)sg.src)[j])
                           : ((const unsigned short*)sg.src)[j];
            }
            ((unsigned short*)sg.dst)[i] = v;
        }
    }
}

// =================== shared-memory union for the mega kernel ===================
union SMem {
    struct { unsigned short agg[16][80]; float ls[256]; float ls2[256]; } l1;
    struct {
        unsigned short raw[2 * 64 * 64];     // ring-2, 64 rows x 64ch
        unsigned short agg2[2][16][72];
        unsigned short iL[25 * 64];          // u16 indices
        float wL[25 * 48];
    } c64;
    struct { float red[256]; float sc[128]; float sh[128]; } ap;
};

// ---- mega: layer-1 conv chunk (16 nodes), fused stats partial ----
__device__ __forceinline__ void conv1_dev(
    const unsigned short* __restrict__ X4, const int* __restrict__ idx,
    const float* __restrict__ wgt, const unsigned short* __restrict__ W,
    const float* __restrict__ bias, float* __restrict__ Of,
    float* __restrict__ part, SMem& sm, int chunk)
{
    const int tid = threadIdx.x;
    const int n0 = chunk * 16;
    for (int p = tid; p < 16 * 25; p += 256) {
        const int r = p / 25;
        const int k = p - r * 25;
        const int n = n0 + r;
        if (n < NN) {
            const int base = n * 75 + k * 3;
            const int i0 = idx[base], i1 = idx[base + 1], i2 = idx[base + 2];
            const float w0 = wgt[base], w1 = wgt[base + 1], w2 = wgt[base + 2];
            const unsigned long long A = *(const unsigned long long*)(X4 + (size_t)i0 * 4);
            const unsigned long long B = *(const unsigned long long*)(X4 + (size_t)i1 * 4);
            const unsigned long long C = *(const unsigned long long*)(X4 + (size_t)i2 * 4);
            #pragma unroll
            for (int e = 0; e < 3; e++) {
                float v = w0 * bf2f((unsigned short)(A >> (16 * e))) +
                          w1 * bf2f((unsigned short)(B >> (16 * e))) +
                          w2 * bf2f((unsigned short)(C >> (16 * e)));
                sm.l1.agg[r][k * 3 + e] = f2bf(v);
            }
        } else {
            #pragma unroll
            for (int e = 0; e < 3; e++) sm.l1.agg[r][k * 3 + e] = 0;
        }
    }
    for (int p = tid; p < 16 * 5; p += 256) {
        const int r = p / 5;
        sm.l1.agg[r][75 + p - r * 5] = 0;
    }
    __syncthreads();

    const int c = tid & 63;
    const int rq = tid >> 6;
    float acc[4] = {};
    const unsigned short* Wr = W + (size_t)c * 80;
    for (int j = 0; j < 80; j += 8) {
        s8v wv = *(const s8v*)(Wr + j);
        float wf[8];
        #pragma unroll
        for (int q = 0; q < 8; q++) wf[q] = bf2f((unsigned short)wv[q]);
        #pragma unroll
        for (int rr = 0; rr < 4; rr++) {
            s8v av = *(const s8v*)(&sm.l1.agg[rq * 4 + rr][j]);
            #pragma unroll
            for (int q = 0; q < 8; q++)
                acc[rr] += wf[q] * bf2f((unsigned short)av[q]);
        }
    }
    const float bb = bias[c];
    float s = 0.f, s2 = 0.f;
    #pragma unroll
    for (int rr = 0; rr < 4; rr++) {
        const int n = n0 + rq * 4 + rr;
        if (n < NN) {
            const float v = acc[rr] + bb;
            Of[(size_t)n * 64 + c] = v;
            s += v; s2 += v * v;
        }
    }
    sm.l1.ls[tid] = s; sm.l1.ls2[tid] = s2;
    __syncthreads();
    if (tid < 64) {
        float a = 0.f, a2 = 0.f;
        #pragma unroll
        for (int g2 = 0; g2 < 4; g2++) {
            a  += sm.l1.ls[g2 * 64 + tid];
            a2 += sm.l1.ls2[g2 * 64 + tid];
        }
        part[(size_t)chunk * 128 + tid] = a;
        part[(size_t)chunk * 128 + 64 + tid] = a2;
    }
    __syncthreads();
}

// ---- mega: DMA conv chunk (CIN=64, ring-2, deduped interp, fused stats) ----
template<int COUTP, int COUT>
__device__ __forceinline__ void convdma_dev(
    const unsigned short* __restrict__ X, const int* __restrict__ idx,
    const float* __restrict__ wgt, const unsigned short* __restrict__ Wt,
    const float* __restrict__ bias, float* __restrict__ pre,
    float* __restrict__ part, SMem& sm, int chunk)
{
    constexpr int CIN = 64;
    constexpr int NT = 2;
    constexpr int NFRAG = COUTP / 64;
    constexpr int Q = 2;                 // DMA insts per wave per slot
    constexpr int R = NT * NFRAG;
    const int tid = threadIdx.x;
    const int n0 = chunk * 16;

    for (int q = tid; q < 16 * 75; q += 256) {
        const int node = q / 75, f = q - node * 75;
        const int k = f / 3, v = f - k * 3;
        const int n = n0 + node;
        const bool ok = n < NN;
        const int g = ok ? (n * 75 + f) : 0;
        sm.c64.iL[k * 64 + node * 4 + v] = ok ? (unsigned short)idx[g] : 0;
        sm.c64.wL[k * 48 + node * 3 + v] = ok ? wgt[g] : 0.f;
    }
    for (int q = tid; q < 25 * 16; q += 256)
        sm.c64.iL[(q / 16) * 64 + (q - (q / 16) * 16) * 4 + 3] = 0;
    __syncthreads();
    waitv<0>();                          // drain cross-stage/chunk VMEM for exact counts

    const int wv = tid >> 6;
    const int lane = tid & 63;
    const int l15 = lane & 15;
    const int kg = lane >> 4;
    const int colbase = wv * NFRAG * 16;

    auto issue = [&](int sd) {
        const int base = (sd & 1) * (64 * CIN);
        #pragma unroll
        for (int jj = 0; jj < Q; jj++) {
            const int j = wv * Q + jj;
            const int row = j * 8 + (lane >> 3);
            const int p = lane & 7;
            const int id = (int)sm.c64.iL[sd * 64 + row];
            gl_lds16(X + (size_t)id * CIN + p * 8, &sm.c64.raw[base + j * 512]);
        }
    };
    auto loadB = [&](int sp, s8v* dst) {
        #pragma unroll
        for (int t = 0; t < NT; t++)
            #pragma unroll
            for (int j = 0; j < NFRAG; j++)
                dst[t * NFRAG + j] = *(const s8v*)(Wt +
                    ((size_t)(sp * 8 + t * 4 + kg) * COUTP + colbase + j * 16 + l15) * 8);
    };

    f32x4 acc[NFRAG] = {};
    s8v breg[2][R];
    issue(0); loadB(0, breg[0]); issue(1);

    #pragma unroll
    for (int s = 0; s < 25; s++) {
        if (s + 1 < 25) loadB(s + 1, breg[(s + 1) & 1]);
        if (s <= 23) waitv<Q + 2 * R>(); else waitv<R>();
        __builtin_amdgcn_s_barrier();
        {
            const int sb = (s & 1) * (64 * CIN);
            const int node = tid >> 4;
            const int e4 = tid & 15;
            const float w0 = sm.c64.wL[s * 48 + node * 3 + 0];
            const float w1 = sm.c64.wL[s * 48 + node * 3 + 1];
            const float w2 = sm.c64.wL[s * 48 + node * 3 + 2];
            const int rb = sb + node * 4 * CIN + e4 * 4;
            const u32x2 A = *(const u32x2*)&sm.c64.raw[rb + 0 * CIN];
            const u32x2 B = *(const u32x2*)&sm.c64.raw[rb + 1 * CIN];
            const u32x2 C = *(const u32x2*)&sm.c64.raw[rb + 2 * CIN];
            const float v0 = w0 * bfu32lo(A[0]) + w1 * bfu32lo(B[0]) + w2 * bfu32lo(C[0]);
            const float v1 = w0 * bfu32hi(A[0]) + w1 * bfu32hi(B[0]) + w2 * bfu32hi(C[0]);
            const float v2 = w0 * bfu32lo(A[1]) + w1 * bfu32lo(B[1]) + w2 * bfu32lo(C[1]);
            const float v3 = w0 * bfu32hi(A[1]) + w1 * bfu32hi(B[1]) + w2 * bfu32hi(C[1]);
            u32x2 o;
            o[0] = cvtpk(v0, v1);
            o[1] = cvtpk(v2, v3);
            *(u32x2*)&sm.c64.agg2[s & 1][node][e4 * 4] = o;
        }
        lgkm0();
        __builtin_amdgcn_s_barrier();
        if (s + 2 < 25) { issue(s + 2); __builtin_amdgcn_sched_barrier(0); }
        #pragma unroll
        for (int t = 0; t < NT; t++) {
            const s8v a = *(const s8v*)(&sm.c64.agg2[s & 1][l15][t * 32 + kg * 8]);
            #pragma unroll
            for (int j = 0; j < NFRAG; j++)
                acc[j] = __builtin_amdgcn_mfma_f32_16x16x32_bf16(
                    a, breg[s & 1][t * NFRAG + j], acc[j], 0, 0, 0);
        }
    }

    #pragma unroll
    for (int j = 0; j < NFRAG; j++) {
        const int col = colbase + j * 16 + l15;
        float s = 0.f, s2 = 0.f;
        const float bb = bias[col];
        #pragma unroll
        for (int q = 0; q < 4; q++) {
            const int n = n0 + kg * 4 + q;
            if (n < NN) {
                const float v = acc[j][q] + bb;
                pre[(size_t)n * COUT + col] = v;
                s += v; s2 += v * v;
            }
        }
        s  += __shfl_xor(s, 16);  s  += __shfl_xor(s, 32);
        s2 += __shfl_xor(s2, 16); s2 += __shfl_xor(s2, 32);
        if (kg == 0) {
            part[(size_t)chunk * 2 * COUT + col] = s;
            part[(size_t)chunk * 2 * COUT + COUT + col] = s2;
        }
    }
    __syncthreads();
}

// ---- mega: parallel partial pre-reduce (641 -> 64 rows) ----
template<int C>
__device__ __forceinline__ void fin1_dev(const float* __restrict__ part,
                                         float* __restrict__ part2)
{
    if (blockIdx.x < 64 && threadIdx.x < 2 * C) {
        float a = 0.f;
        for (int r = blockIdx.x; r < 641; r += 64)
            a += part[(size_t)r * 2 * C + threadIdx.x];
        part2[(size_t)blockIdx.x * 2 * C + threadIdx.x] = a;
    }
}

// ---- mega: per-block scsh from part2, then grid-stride BN+ReLU apply ----
template<int C>
__device__ __forceinline__ void apply_dev(const float* __restrict__ pre,
                                          const float* __restrict__ part2,
                                          const float* __restrict__ gm,
                                          const float* __restrict__ bt,
                                          unsigned short* __restrict__ act,
                                          SMem& sm)
{
    const int tid = threadIdx.x;
    if (tid < 2 * C) {
        float a = 0.f;
        #pragma unroll 8
        for (int g2 = 0; g2 < 64; g2++) a += part2[g2 * 2 * C + tid];
        sm.ap.red[tid] = a;
    }
    __syncthreads();
    if (tid < C) {
        const float inv = 1.f / (float)NN;
        float mu = sm.ap.red[tid] * inv;
        float var = sm.ap.red[C + tid] * inv - mu * mu;
        float sc = gm[tid] * rsqrtf(var + 1e-5f);
        sm.ap.sc[tid] = sc;
        sm.ap.sh[tid] = bt[tid] - mu * sc;
    }
    __syncthreads();
    constexpr int TOTAL4 = NN * C / 4;
    for (int i = blockIdx.x * 256 + tid; i < TOTAL4; i += 512 * 256) {
        const f32x4 v = *(const f32x4*)(pre + (size_t)i * 4);
        const int c0 = (i * 4) % C;
        u32x2 o;
        o[0] = cvtpk(fmaxf(v[0] * sm.ap.sc[c0]     + sm.ap.sh[c0],     0.f),
                     fmaxf(v[1] * sm.ap.sc[c0 + 1] + sm.ap.sh[c0 + 1], 0.f));
        o[1] = cvtpk(fmaxf(v[2] * sm.ap.sc[c0 + 2] + sm.ap.sh[c0 + 2], 0.f),
                     fmaxf(v[3] * sm.ap.sc[c0 + 3] + sm.ap.sh[c0 + 3], 0.f));
        *(u32x2*)(act + (size_t)i * 4) = o;
    }
    __syncthreads();
}

struct MP {
    const unsigned short* x4; const int* idx; const float* wgt;
    const unsigned short* W1; const unsigned short* Wt2; const unsigned short* Wt3;
    const float* biasc; float* pre; unsigned short* actA; unsigned short* actB;
    float* part; float* part2;
};

__global__ __launch_bounds__(256, 2) void mega_k(MP p) {
    __shared__ SMem sm;
    cg::grid_group gg = cg::this_grid();
    // layer 1
    for (int c = blockIdx.x; c < 641; c += 512)
        conv1_dev(p.x4, p.idx, p.wgt, p.W1, p.biasc + 0, p.pre, p.part, sm, c);
    gg.sync();
    fin1_dev<64>(p.part, p.part2);
    gg.sync();
    apply_dev<64>(p.pre, p.part2, p.biasc + 64, p.biasc + 128, p.actA, sm);
    gg.sync();
    // layer 2
    for (int c = blockIdx.x; c < 641; c += 512)
        convdma_dev<64, 64>(p.actA, p.idx, p.wgt, p.Wt2, p.biasc + 192, p.pre, p.part, sm, c);
    gg.sync();
    fin1_dev<64>(p.part, p.part2);
    gg.sync();
    apply_dev<64>(p.pre, p.part2, p.biasc + 256, p.biasc + 320, p.actB, sm);
    gg.sync();
    // layer 3
    for (int c = blockIdx.x; c < 641; c += 512)
        convdma_dev<128, 128>(p.actB, p.idx, p.wgt, p.Wt3, p.biasc + 384, p.pre, p.part, sm, c);
    gg.sync();
    fin1_dev<128>(p.part, p.part2);
    gg.sync();
    apply_dev<128>(p.pre, p.part2, p.biasc + 512, p.biasc + 640, p.actA, sm);
}

// =================== round-15 kernels (fallback path + layer 4) ===================

template<int CIN4, int COUT, int CG, int NB>
__global__ __launch_bounds__(256) void conv1_k(
    const unsigned short* __restrict__ X4, const int* __restrict__ idx,
    const float* __restrict__ wgt, const unsigned short* __restrict__ W,
    const float* __restrict__ bias, float* __restrict__ Of, float* __restrict__ part)
{
    __shared__ SMem sm;
    conv1_dev(X4, idx, wgt, W, bias, Of, part, sm, blockIdx.x);
}

template<int CIN, int COUTP, int COUT, int RING, bool FINAL>
__global__ __launch_bounds__(256, 3) void convdma2_k(
    const unsigned short* __restrict__ X,
    const int* __restrict__ idx,
    const float* __restrict__ wgt,
    const unsigned short* __restrict__ Wt,
    const float* __restrict__ bias,
    float* __restrict__ pre,
    void* __restrict__ Ob,
    const int* __restrict__ flag,
    float* __restrict__ part)
{
    constexpr int NT = CIN / 32;
    constexpr int NFRAG = COUTP / 64;
    constexpr int INSTS = CIN / 8;
    constexpr int Q = INSTS / 4;
    constexpr int R = NT * NFRAG;
    constexpr int UPNS = (CIN == 64) ? 4 : 5;
    constexpr int UNITS = 16 << UPNS;
    __shared__ unsigned short raw[RING * 64 * CIN];
    __shared__ unsigned short agg[2][16][CIN + 8];
    __shared__ int   iL[25 * 64];
    __shared__ float wL[25 * 48];
    const int tid = threadIdx.x;
    const int n0 = blockIdx.x * 16;

    for (int q = tid; q < 16 * 75; q += 256) {
        const int node = q / 75, f = q - node * 75;
        const int k = f / 3, v = f - k * 3;
        const int n = n0 + node;
        const bool ok = n < NN;
        const int g = ok ? (n * 75 + f) : 0;
        iL[k * 64 + node * 4 + v] = ok ? idx[g] : 0;
        wL[k * 48 + node * 3 + v] = ok ? wgt[g] : 0.f;
    }
    for (int q = tid; q < 25 * 16; q += 256)
        iL[(q / 16) * 64 + (q - (q / 16) * 16) * 4 + 3] = 0;
    __syncthreads();

    const int wv = tid >> 6;
    const int lane = tid & 63;
    const int l15 = lane & 15;
    const int kg = lane >> 4;
    const int colbase = wv * NFRAG * 16;

    auto issue = [&](int sd) {
        const int base = (sd & (RING - 1)) * (64 * CIN);
        #pragma unroll
        for (int jj = 0; jj < Q; jj++) {
            const int j = wv * Q + jj;
            int row, p;
            if constexpr (CIN == 64) { row = j * 8 + (lane >> 3); p = lane & 7; }
            else                     { row = j * 4 + (lane >> 4); p = lane & 15; }
            const int id = iL[sd * 64 + row];
            gl_lds16(X + (size_t)id * CIN + p * 8, &raw[base + j * 512]);
        }
    };
    auto loadB = [&](int sp, s8v* dst) {
        #pragma unroll
        for (int t = 0; t < NT; t++)
            #pragma unroll
            for (int j = 0; j < NFRAG; j++)
                dst[t * NFRAG + j] = *(const s8v*)(Wt +
                    ((size_t)(sp * (CIN / 8) + t * 4 + kg) * COUTP + colbase + j * 16 + l15) * 8);
    };

    f32x4 acc[NFRAG] = {};
    s8v breg[2][R];

    if constexpr (RING == 4) { issue(0); issue(1); loadB(0, breg[0]); issue(2); }
    else                     { issue(0); loadB(0, breg[0]); issue(1); }

    #pragma unroll
    for (int s = 0; s < 25; s++) {
        if (s + 1 < 25) loadB(s + 1, breg[(s + 1) & 1]);
        if constexpr (RING == 4) {
            if (s <= 22)      waitv<2 * Q + 2 * R>();
            else if (s == 23) waitv<Q + 2 * R>();
            else              waitv<R>();
        } else {
            if (s <= 23)      waitv<Q + 2 * R>();
            else              waitv<R>();
        }
        __builtin_amdgcn_s_barrier();
        {
            const int sb = (s & (RING - 1)) * (64 * CIN);
            #pragma unroll
            for (int u = tid; u < UNITS; u += 256) {
                const int node = u >> UPNS;
                const int e4 = u & ((1 << UPNS) - 1);
                const float w0 = wL[s * 48 + node * 3 + 0];
                const float w1 = wL[s * 48 + node * 3 + 1];
                const float w2 = wL[s * 48 + node * 3 + 2];
                const int rb = sb + node * 4 * CIN + e4 * 4;
                const u32x2 A = *(const u32x2*)&raw[rb + 0 * CIN];
                const u32x2 B = *(const u32x2*)&raw[rb + 1 * CIN];
                const u32x2 C = *(const u32x2*)&raw[rb + 2 * CIN];
                const float v0 = w0 * bfu32lo(A[0]) + w1 * bfu32lo(B[0]) + w2 * bfu32lo(C[0]);
                const float v1 = w0 * bfu32hi(A[0]) + w1 * bfu32hi(B[0]) + w2 * bfu32hi(C[0]);
                const float v2 = w0 * bfu32lo(A[1]) + w1 * bfu32lo(B[1]) + w2 * bfu32lo(C[1]);
                const float v3 = w0 * bfu32hi(A[1]) + w1 * bfu32hi(B[1]) + w2 * bfu32hi(C[1]);
                u32x2 o;
                o[0] = cvtpk(v0, v1);
                o[1] = cvtpk(v2, v3);
                *(u32x2*)&agg[s & 1][node][e4 * 4] = o;
            }
        }
        if constexpr (RING == 4) { if (s + 3 < 25) issue(s + 3); }
        lgkm0();
        __builtin_amdgcn_s_barrier();
        if constexpr (RING == 2) {
            if (s + 2 < 25) issue(s + 2);
            __builtin_amdgcn_sched_barrier(0);
        }
        #pragma unroll
        for (int t = 0; t < NT; t++) {
            const s8v a = *(const s8v*)(&agg[s & 1][l15][t * 32 + kg * 8]);
            #pragma unroll
            for (int j = 0; j < NFRAG; j++)
                acc[j] = __builtin_amdgcn_mfma_f32_16x16x32_bf16(
                    a, breg[s & 1][t * NFRAG + j], acc[j], 0, 0, 0);
        }
    }

    bool f32o = false;
    if constexpr (FINAL) f32o = (*flag != 0);
    #pragma unroll
    for (int j = 0; j < NFRAG; j++) {
        const int col = colbase + j * 16 + l15;
        float s = 0.f, s2 = 0.f;
        if (col < COUT) {
            const float bb = bias[col];
            #pragma unroll
            for (int q = 0; q < 4; q++) {
                const int n = n0 + kg * 4 + q;
                if (n < NN) {
                    const float v = acc[j][q] + bb;
                    if constexpr (FINAL) {
                        if (f32o) ((float*)Ob)[(size_t)n * COUT + col] = v;
                        else ((unsigned short*)Ob)[(size_t)n * COUT + col] = f2bf(v);
                    } else {
                        pre[(size_t)n * COUT + col] = v;
                        s += v; s2 += v * v;
                    }
                }
            }
        }
        if constexpr (!FINAL) {
            s  += __shfl_xor(s, 16);  s  += __shfl_xor(s, 32);
            s2 += __shfl_xor(s2, 16); s2 += __shfl_xor(s2, 32);
            if (kg == 0) {
                part[(size_t)blockIdx.x * 2 * COUT + col] = s;
                part[(size_t)blockIdx.x * 2 * COUT + COUT + col] = s2;
            }
        }
    }
}

template<int C, int NBLK>
__global__ __launch_bounds__(1024) void fin_k(
    const float* __restrict__ part, const float* __restrict__ gm,
    const float* __restrict__ bt, float* __restrict__ scsh)
{
    constexpr int RG = 1024 / C;
    __shared__ float ls[1024], ls2[1024];
    const int c = threadIdx.x % C;
    const int g = threadIdx.x / C;
    float s = 0.f, s2 = 0.f;
    for (int b = g; b < NBLK; b += RG) {
        s  += part[(size_t)b * 2 * C + c];
        s2 += part[(size_t)b * 2 * C + C + c];
    }
    ls[threadIdx.x] = s; ls2[threadIdx.x] = s2;
    __syncthreads();
    if (threadIdx.x < C) {
        float a = 0.f, a2 = 0.f;
        #pragma unroll
        for (int g2 = 0; g2 < RG; g2++) {
            a  += ls[g2 * C + threadIdx.x];
            a2 += ls2[g2 * C + threadIdx.x];
        }
        const float inv = 1.f / (float)NN;
        float mu = a * inv;
        float var = a2 * inv - mu * mu;
        float scale = gm[threadIdx.x] * rsqrtf(var + 1e-5f);
        scsh[threadIdx.x] = scale;
        scsh[C + threadIdx.x] = bt[threadIdx.x] - mu * scale;
    }
}

template<int C>
__global__ __launch_bounds__(256) void bnap_k(
    const float* __restrict__ pre, const float* __restrict__ scsh,
    unsigned short* __restrict__ act)
{
    __shared__ float sc[C], sh[C];
    if (threadIdx.x < C) {
        sc[threadIdx.x] = scsh[threadIdx.x];
        sh[threadIdx.x] = scsh[C + threadIdx.x];
    }
    __syncthreads();
    constexpr int TOTAL4 = NN * C / 4;
    const int stride = gridDim.x * 256;
    for (int i = blockIdx.x * 256 + threadIdx.x; i < TOTAL4; i += stride) {
        const f32x4 v = *(const f32x4*)(pre + (size_t)i * 4);
        const int c0 = (i * 4) % C;
        u32x2 o;
        o[0] = cvtpk(fmaxf(v[0] * sc[c0]     + sh[c0],     0.f),
                     fmaxf(v[1] * sc[c0 + 1] + sh[c0 + 1], 0.f));
        o[1] = cvtpk(fmaxf(v[2] * sc[c0 + 2] + sh[c0 + 2], 0.f),
                     fmaxf(v[3] * sc[c0 + 3] + sh[c0 + 3], 0.f));
        *(u32x2*)(act + (size_t)i * 4) = o;
    }
}

extern "C" void kernel_launch(void* const* d_in, const int* in_sizes, int n_in,
                              void* d_out, int out_size, void* d_ws, size_t ws_size,
                              hipStream_t stream) {
    const void* x    = d_in[0];
    const int*  idx  = (const int*)d_in[1];
    const void* wgt  = d_in[2];
    const void* W1   = d_in[3];
    const void* b1   = d_in[4];
    const void* g1   = d_in[5];
    const void* be1  = d_in[6];
    const void* W2   = d_in[7];
    const void* b2   = d_in[8];
    const void* g2   = d_in[9];
    const void* be2  = d_in[10];
    const void* W3   = d_in[11];
    const void* b3   = d_in[12];
    const void* g3   = d_in[13];
    const void* be3  = d_in[14];
    const void* Wout = d_in[15];
    const void* bout = d_in[16];

    char* ws = (char*)d_ws;
    size_t off = 0;
    auto alloc = [&](size_t bytes) {
        off = (off + 255) & ~(size_t)255;
        size_t o = off; off += bytes; return o;
    };
    const size_t o_flag  = alloc(4);
    const size_t o_x4    = alloc((size_t)NN * 4 * 2);
    const size_t o_wgtc  = alloc((size_t)NN * 75 * 4);
    const size_t o_W1c   = alloc(64 * 80 * 2);
    const size_t o_Wt2   = alloc((size_t)200 * 64 * 8 * 2);
    const size_t o_Wt3   = alloc((size_t)200 * 128 * 8 * 2);
    const size_t o_Wt4   = alloc((size_t)400 * 64 * 8 * 2);
    const size_t o_bias  = alloc(1024 * 4);
    const size_t o_pre   = alloc((size_t)NN * 128 * 4);
    const size_t o_actA  = alloc((size_t)NN * 128 * 2);
    const size_t o_actB  = alloc((size_t)NN * 64 * 2);
    const size_t o_part  = alloc((size_t)641 * 2 * 128 * 4);
    const size_t o_part2 = alloc((size_t)64 * 2 * 128 * 4);
    const size_t o_scsh  = alloc(2 * 128 * 4);
    if (ws_size < off) return;

    int* flag = (int*)(ws + o_flag);
    unsigned short* x4  = (unsigned short*)(ws + o_x4);
    float* wgtc = (float*)(ws + o_wgtc);
    unsigned short* W1c = (unsigned short*)(ws + o_W1c);
    unsigned short* Wt2 = (unsigned short*)(ws + o_Wt2);
    unsigned short* Wt3 = (unsigned short*)(ws + o_Wt3);
    unsigned short* Wt4 = (unsigned short*)(ws + o_Wt4);
    float* biasc = (float*)(ws + o_bias);
    float* pre  = (float*)(ws + o_pre);
    unsigned short* actA = (unsigned short*)(ws + o_actA);
    unsigned short* actB = (unsigned short*)(ws + o_actB);
    float* part  = (float*)(ws + o_part);
    float* part2 = (float*)(ws + o_part2);
    float* scsh  = (float*)(ws + o_scsh);

    detect_k<<<1, 64, 0, stream>>>(wgt, flag);

    Tab t;
    t.s[0]  = { x,    x4,   NN * 4,         NN * 3,  4, 0, 0, 0 };
    t.s[1]  = { wgt,  wgtc, NN * 75,        NN * 75, 1, 0, 0, 0 };
    t.s[2]  = { W1,   W1c,  64 * 80,        64 * 80, 2, 0, 0, 0 };
    t.s[3]  = { W2,   Wt2,  200 * 64 * 8,   0,       3, 1600, 64, 64 };
    t.s[4]  = { W3,   Wt3,  200 * 128 * 8,  0,       3, 1600, 128, 128 };
    t.s[5]  = { Wout, Wt4,  400 * 64 * 8,   0,       3, 3200, 36, 64 };
    t.s[6]  = { b1,   biasc + 0,   64, 64, 1, 0, 0, 0 };
    t.s[7]  = { g1,   biasc + 64,  64, 64, 1, 0, 0, 0 };
    t.s[8]  = { be1,  biasc + 128, 64, 64, 1, 0, 0, 0 };
    t.s[9]  = { b2,   biasc + 192, 64, 64, 1, 0, 0, 0 };
    t.s[10] = { g2,   biasc + 256, 64, 64, 1, 0, 0, 0 };
    t.s[11] = { be2,  biasc + 320, 64, 64, 1, 0, 0, 0 };
    t.s[12] = { b3,   biasc + 384, 128, 128, 1, 0, 0, 0 };
    t.s[13] = { g3,   biasc + 512, 128, 128, 1, 0, 0, 0 };
    t.s[14] = { be3,  biasc + 640, 128, 128, 1, 0, 0, 0 };
    t.s[15] = { bout, biasc + 768, 36, 36, 1, 0, 0, 0 };
    canon_k<<<dim3(768, 16), 256, 0, stream>>>(t, flag);

    dim3 B(256);
    MP P;
    P.x4 = x4; P.idx = idx; P.wgt = wgtc; P.W1 = W1c; P.Wt2 = Wt2; P.Wt3 = Wt3;
    P.biasc = biasc; P.pre = pre; P.actA = actA; P.actB = actB;
    P.part = part; P.part2 = part2;
    void* margs[] = { &P };
    hipError_t e = hipLaunchCooperativeKernel((void*)mega_k, dim3(512), dim3(256),
                                              margs, 0, stream);
    if (e != hipSuccess) {
        (void)hipGetLastError();
        // fallback: proven round-15 dispatch chain (L1..L3 + BN)
        conv1_k<4, 64, 64, 16><<<641, B, 0, stream>>>(x4, idx, wgtc, W1c, biasc + 0, pre, part);
        fin_k<64, 641><<<1, 1024, 0, stream>>>(part, biasc + 64, biasc + 128, scsh);
        bnap_k<64><<<512, B, 0, stream>>>(pre, scsh, actA);
        convdma2_k<64, 64, 64, 4, false><<<641, B, 0, stream>>>(
            actA, idx, wgtc, Wt2, biasc + 192, pre, nullptr, flag, part);
        fin_k<64, 641><<<1, 1024, 0, stream>>>(part, biasc + 256, biasc + 320, scsh);
        bnap_k<64><<<512, B, 0, stream>>>(pre, scsh, actB);
        convdma2_k<64, 128, 128, 4, false><<<641, B, 0, stream>>>(
            actB, idx, wgtc, Wt3, biasc + 384, pre, nullptr, flag, part);
        fin_k<128, 641><<<1, 1024, 0, stream>>>(part, biasc + 512, biasc + 640, scsh);
        bnap_k<128><<<512, B, 0, stream>>>(pre, scsh, actA);
    }
    // layer 4: 128 -> 36 (COUTP=64, ring-2), direct to d_out (both paths)
    convdma2_k<128, 64, 36, 2, true><<<641, B, 0, stream>>>(
        actA, idx, wgtc, Wt4, biasc + 768, nullptr, d_out, flag, nullptr);
}

// Round 17
// 157.841 us; speedup vs baseline: 3.8942x; 3.8942x over previous
//
#include <hip/hip_runtime.h>

#define NN 10242

typedef short s8v __attribute__((ext_vector_type(8)));
typedef unsigned int u32x2 __attribute__((ext_vector_type(2)));
typedef float f32x4 __attribute__((ext_vector_type(4)));

static __device__ __forceinline__ float bf2f(unsigned short u) {
    unsigned int i = ((unsigned int)u) << 16;
    return __builtin_bit_cast(float, i);
}
static __device__ __forceinline__ float bfu32lo(unsigned int d) {
    return __builtin_bit_cast(float, d << 16);
}
static __device__ __forceinline__ float bfu32hi(unsigned int d) {
    return __builtin_bit_cast(float, d & 0xffff0000u);
}
static __device__ __forceinline__ unsigned short f2bf(float f) {
    unsigned int i = __builtin_bit_cast(unsigned int, f);
    unsigned int lsb = (i >> 16) & 1u;
    i += 0x7fffu + lsb;
    return (unsigned short)(i >> 16);
}
static __device__ __forceinline__ unsigned int cvtpk(float lo, float hi) {
    unsigned int r;
    asm("v_cvt_pk_bf16_f32 %0, %1, %2" : "=v"(r) : "v"(lo), "v"(hi));
    return r;
}
static __device__ __forceinline__ void gl_lds16(const unsigned short* g, unsigned short* l) {
    __builtin_amdgcn_global_load_lds(
        (const __attribute__((address_space(1))) unsigned int*)g,
        (__attribute__((address_space(3))) unsigned int*)l, 16, 0, 0);
}
template<int N> static __device__ __forceinline__ void waitv() {
    asm volatile("s_waitcnt vmcnt(%0)" :: "n"(N) : "memory");
    __builtin_amdgcn_sched_barrier(0);
}
static __device__ __forceinline__ void lgkm0() {
    asm volatile("s_waitcnt lgkmcnt(0)" ::: "memory");
    __builtin_amdgcn_sched_barrier(0);
}
static __device__ __forceinline__ int imin(int a, int b) { return a < b ? a : b; }

// ---- dtype detector ----
__global__ void detect_k(const void* __restrict__ wgt, int* __restrict__ flag) {
    const float* wf = (const float*)wgt;
    const int r = threadIdx.x;
    float s = wf[3 * r] + wf[3 * r + 1] + wf[3 * r + 2];
    bool ok = (s == s) && (fabsf(s - 1.f) < 0.05f);
    unsigned long long m = __ballot(ok);
    if (r == 0) *flag = (__popcll(m) >= 60) ? 1 : 0;
}

// ---- canonicalizer ----
struct Seg { const void* src; void* dst; int n; int nsrc; int mode; int K; int cout; int cpad; };
struct Tab { Seg s[16]; };

__global__ __launch_bounds__(256) void canon_k(Tab t, const int* __restrict__ flag) {
    const Seg sg = t.s[blockIdx.y];
    const bool f32src = (*flag != 0);
    for (int i = blockIdx.x * 256 + threadIdx.x; i < sg.n; i += gridDim.x * 256) {
        if (sg.mode == 0) {
            unsigned short v = 0;
            if (i < sg.nsrc)
                v = f32src ? f2bf(((const float*)sg.src)[i])
                           : ((const unsigned short*)sg.src)[i];
            ((unsigned short*)sg.dst)[i] = v;
        } else if (sg.mode == 1) {
            float v = f32src ? ((const float*)sg.src)[i]
                             : bf2f(((const unsigned short*)sg.src)[i]);
            ((float*)sg.dst)[i] = v;
        } else if (sg.mode == 2) {
            const int row = i / 80, col = i - row * 80;
            unsigned short v = 0;
            if (col < 75) {
                const int j = row * 75 + col;
                v = f32src ? f2bf(((const float*)sg.src)[j])
                           : ((const unsigned short*)sg.src)[j];
            }
            ((unsigned short*)sg.dst)[i] = v;
        } else if (sg.mode == 3) {
            const int e = i & 7;
            const int r = i >> 3;
            const int c = r % sg.cpad;
            const int k8 = r / sg.cpad;
            unsigned short v = 0;
            if (c < sg.cout) {
                const int j = c * sg.K + k8 * 8 + e;
                v = f32src ? f2bf(((const float*)sg.src)[j])
                           : ((const unsigned short*)sg.src)[j];
            }
            ((unsigned short*)sg.dst)[i] = v;
        } else {
            const int row = i >> 2, col = i & 3;
            unsigned short v = 0;
            if (col < 3) {
                const int j = row * 3 + col;
                v = f32src ? f2bf(((const float*)sg.src)[j])
                           : ((const unsigned short*)sg.src)[j];
            }
            ((unsigned short*)sg.dst)[i] = v;
        }
    }
}

// ---- layer-1 conv (K=80, VALU) + fused per-block stats partials ----
template<int CIN4, int COUT, int CG, int NB>
__global__ __launch_bounds__(256) void conv1_k(
    const unsigned short* __restrict__ X4,
    const int* __restrict__ idx,
    const float* __restrict__ wgt,
    const unsigned short* __restrict__ W,
    const float* __restrict__ bias,
    float* __restrict__ Of,
    float* __restrict__ part)
{
    constexpr int K = 75;
    constexpr int KPAD = 80;
    __shared__ unsigned short agg[NB][KPAD];
    __shared__ float ls[256], ls2[256];
    const int tid = threadIdx.x;
    const int n0 = blockIdx.x * NB;

    for (int p = tid; p < NB * 25; p += 256) {
        const int r = p / 25;
        const int k = p - r * 25;
        const int n = n0 + r;
        if (n < NN) {
            const int base = n * 75 + k * 3;
            const int i0 = idx[base], i1 = idx[base + 1], i2 = idx[base + 2];
            const float w0 = wgt[base], w1 = wgt[base + 1], w2 = wgt[base + 2];
            const unsigned long long A = *(const unsigned long long*)(X4 + (size_t)i0 * 4);
            const unsigned long long B = *(const unsigned long long*)(X4 + (size_t)i1 * 4);
            const unsigned long long C = *(const unsigned long long*)(X4 + (size_t)i2 * 4);
            #pragma unroll
            for (int e = 0; e < 3; e++) {
                float v = w0 * bf2f((unsigned short)(A >> (16 * e))) +
                          w1 * bf2f((unsigned short)(B >> (16 * e))) +
                          w2 * bf2f((unsigned short)(C >> (16 * e)));
                agg[r][k * 3 + e] = f2bf(v);
            }
        } else {
            #pragma unroll
            for (int e = 0; e < 3; e++) agg[r][k * 3 + e] = 0;
        }
    }
    for (int p = tid; p < NB * (KPAD - K); p += 256) {
        const int r = p / (KPAD - K);
        agg[r][K + p - r * (KPAD - K)] = 0;
    }
    __syncthreads();

    constexpr int RG = 256 / CG;
    constexpr int RPT = NB / RG;
    const int c = tid % CG;
    const int rq = tid / CG;
    float acc[RPT] = {};
    const unsigned short* Wr = W + (size_t)c * KPAD;
    for (int j = 0; j < KPAD; j += 8) {
        s8v wv = *(const s8v*)(Wr + j);
        float wf[8];
        #pragma unroll
        for (int q = 0; q < 8; q++) wf[q] = bf2f((unsigned short)wv[q]);
        #pragma unroll
        for (int rr = 0; rr < RPT; rr++) {
            s8v av = *(const s8v*)(&agg[rq * RPT + rr][j]);
            #pragma unroll
            for (int q = 0; q < 8; q++)
                acc[rr] += wf[q] * bf2f((unsigned short)av[q]);
        }
    }
    const float bb = bias[c];
    float s = 0.f, s2 = 0.f;
    #pragma unroll
    for (int rr = 0; rr < RPT; rr++) {
        const int n = n0 + rq * RPT + rr;
        if (n < NN) {
            const float v = acc[rr] + bb;
            Of[(size_t)n * COUT + c] = v;
            s += v; s2 += v * v;
        }
    }
    ls[tid] = s; ls2[tid] = s2;
    __syncthreads();
    if (tid < COUT) {
        float a = 0.f, a2 = 0.f;
        #pragma unroll
        for (int g2 = 0; g2 < RG; g2++) {
            a  += ls[g2 * CG + tid];
            a2 += ls2[g2 * CG + tid];
        }
        part[(size_t)blockIdx.x * 2 * COUT + tid] = a;
        part[(size_t)blockIdx.x * 2 * COUT + COUT + tid] = a2;
    }
}

// ---- grouped DMA conv (CIN=64, ring-4, 2 slots/iteration, XOR-swizzled raw) ----
template<int COUTP, int COUT>
__global__ __launch_bounds__(256, 3) void convg_k(
    const unsigned short* __restrict__ X,
    const int* __restrict__ idx,
    const float* __restrict__ wgt,
    const unsigned short* __restrict__ Wt,   // [200][COUTP][8]
    const float* __restrict__ bias,
    float* __restrict__ pre,
    float* __restrict__ part)
{
    constexpr int CIN = 64;
    constexpr int NT = 2;
    constexpr int NFRAG = COUTP / 64;
    constexpr int Q = 2;                     // DMA insts per wave per slot
    constexpr int R = NT * NFRAG;            // B-frag loads per wave per slot
    __shared__ unsigned short raw[4 * 64 * CIN];
    __shared__ unsigned short agg[2][16][CIN + 8];
    __shared__ unsigned short iL[25 * 64];
    __shared__ float wL[25 * 48];
    const int tid = threadIdx.x;
    const int n0 = blockIdx.x * 16;

    for (int q = tid; q < 16 * 75; q += 256) {
        const int node = q / 75, f = q - node * 75;
        const int k = f / 3, v = f - k * 3;
        const int n = n0 + node;
        const bool ok = n < NN;
        const int g = ok ? (n * 75 + f) : 0;
        iL[k * 64 + node * 4 + v] = ok ? (unsigned short)idx[g] : 0;
        wL[k * 48 + node * 3 + v] = ok ? wgt[g] : 0.f;
    }
    for (int q = tid; q < 25 * 16; q += 256)
        iL[(q / 16) * 64 + (q - (q / 16) * 16) * 4 + 3] = 0;
    __syncthreads();

    const int wv = tid >> 6;
    const int lane = tid & 63;
    const int l15 = lane & 15;
    const int kg = lane >> 4;
    const int colbase = wv * NFRAG * 16;

    // DMA: source chunk XOR-swizzled by node (row>>2); dest linear
    auto issue = [&](int sd) {
        const int base = (sd & 3) * (64 * CIN);
        #pragma unroll
        for (int jj = 0; jj < Q; jj++) {
            const int j = wv * Q + jj;
            const int row = j * 8 + (lane >> 3);
            const int p = lane & 7;
            const int ch = p ^ ((row >> 2) & 7);
            const int id = (int)iL[sd * 64 + row];
            gl_lds16(X + (size_t)id * CIN + ch * 8, &raw[base + j * 512]);
        }
    };
    auto loadB = [&](int sp, s8v* dst) {
        #pragma unroll
        for (int t = 0; t < NT; t++)
            #pragma unroll
            for (int j = 0; j < NFRAG; j++)
                dst[t * NFRAG + j] = *(const s8v*)(Wt +
                    ((size_t)(sp * 8 + t * 4 + kg) * COUTP + colbase + j * 16 + l15) * 8);
    };
    // interp one slot (parity par); matches DMA swizzle
    auto interp = [&](int s, int par) {
        const int sb = (s & 3) * (64 * CIN);
        const int node = tid >> 4;
        const int e4 = tid & 15;
        const float w0 = wL[s * 48 + node * 3 + 0];
        const float w1 = wL[s * 48 + node * 3 + 1];
        const float w2 = wL[s * 48 + node * 3 + 2];
        const int chunk = (e4 >> 1) ^ (node & 7);
        const int off = chunk * 8 + (e4 & 1) * 4;
        const int rb = sb + node * 4 * CIN + off;
        const u32x2 A = *(const u32x2*)&raw[rb + 0 * CIN];
        const u32x2 B = *(const u32x2*)&raw[rb + 1 * CIN];
        const u32x2 C = *(const u32x2*)&raw[rb + 2 * CIN];
        const float v0 = w0 * bfu32lo(A[0]) + w1 * bfu32lo(B[0]) + w2 * bfu32lo(C[0]);
        const float v1 = w0 * bfu32hi(A[0]) + w1 * bfu32hi(B[0]) + w2 * bfu32hi(C[0]);
        const float v2 = w0 * bfu32lo(A[1]) + w1 * bfu32lo(B[1]) + w2 * bfu32lo(C[1]);
        const float v3 = w0 * bfu32hi(A[1]) + w1 * bfu32hi(B[1]) + w2 * bfu32hi(C[1]);
        u32x2 o;
        o[0] = cvtpk(v0, v1);
        o[1] = cvtpk(v2, v3);
        *(u32x2*)&agg[par][node][e4 * 4] = o;
    };

    f32x4 acc[NFRAG] = {};
    s8v breg[2][2][R];                       // [group parity][slot parity][R]

    // prologue
    issue(0); issue(1);
    loadB(0, breg[0][0]); loadB(1, breg[0][1]);
    issue(2); issue(3);

    #pragma unroll
    for (int g = 0; g < 12; g++) {
        const int s0 = 2 * g, s1 = 2 * g + 1;
        if (g < 11) { loadB(s0 + 2, breg[(g + 1) & 1][0]); loadB(s0 + 3, breg[(g + 1) & 1][1]); }
        else        { loadB(24, breg[(g + 1) & 1][0]); }
        if (g <= 10) waitv<2 * Q + 2 * R>(); else waitv<Q + R>();
        __builtin_amdgcn_s_barrier();        // raw[s0], raw[s1] landed for all
        interp(s0, 0);
        interp(s1, 1);
        lgkm0();
        __builtin_amdgcn_s_barrier();        // agg complete; raw[s0],raw[s1] free
        if (s0 + 4 < 25) issue(s0 + 4);
        if (s0 + 5 < 25) issue(s0 + 5);
        __builtin_amdgcn_sched_barrier(0);
        #pragma unroll
        for (int t = 0; t < NT; t++) {
            const s8v a0 = *(const s8v*)(&agg[0][l15][t * 32 + kg * 8]);
            #pragma unroll
            for (int j = 0; j < NFRAG; j++)
                acc[j] = __builtin_amdgcn_mfma_f32_16x16x32_bf16(
                    a0, breg[g & 1][0][t * NFRAG + j], acc[j], 0, 0, 0);
        }
        #pragma unroll
        for (int t = 0; t < NT; t++) {
            const s8v a1 = *(const s8v*)(&agg[1][l15][t * 32 + kg * 8]);
            #pragma unroll
            for (int j = 0; j < NFRAG; j++)
                acc[j] = __builtin_amdgcn_mfma_f32_16x16x32_bf16(
                    a1, breg[g & 1][1][t * NFRAG + j], acc[j], 0, 0, 0);
        }
    }
    // tail: slot 24 (breg[0][0])
    waitv<0>();
    __builtin_amdgcn_s_barrier();
    interp(24, 0);
    lgkm0();
    __builtin_amdgcn_s_barrier();
    #pragma unroll
    for (int t = 0; t < NT; t++) {
        const s8v a = *(const s8v*)(&agg[0][l15][t * 32 + kg * 8]);
        #pragma unroll
        for (int j = 0; j < NFRAG; j++)
            acc[j] = __builtin_amdgcn_mfma_f32_16x16x32_bf16(
                a, breg[0][0][t * NFRAG + j], acc[j], 0, 0, 0);
    }

    #pragma unroll
    for (int j = 0; j < NFRAG; j++) {
        const int col = colbase + j * 16 + l15;
        float s = 0.f, s2 = 0.f;
        const float bb = bias[col];
        #pragma unroll
        for (int q = 0; q < 4; q++) {
            const int n = n0 + kg * 4 + q;           // C row = (lane>>4)*4 + reg
            if (n < NN) {
                const float v = acc[j][q] + bb;
                pre[(size_t)n * COUT + col] = v;
                s += v; s2 += v * v;
            }
        }
        s  += __shfl_xor(s, 16);  s  += __shfl_xor(s, 32);
        s2 += __shfl_xor(s2, 16); s2 += __shfl_xor(s2, 32);
        if (kg == 0) {
            part[(size_t)blockIdx.x * 2 * COUT + col] = s;
            part[(size_t)blockIdx.x * 2 * COUT + COUT + col] = s2;
        }
    }
}

// ---- round-15 DMA conv (used for layer 4, CIN=128, ring-2) ----
template<int CIN, int COUTP, int COUT, int RING, bool FINAL>
__global__ __launch_bounds__(256, 3) void convdma2_k(
    const unsigned short* __restrict__ X,
    const int* __restrict__ idx,
    const float* __restrict__ wgt,
    const unsigned short* __restrict__ Wt,
    const float* __restrict__ bias,
    float* __restrict__ pre,
    void* __restrict__ Ob,
    const int* __restrict__ flag,
    float* __restrict__ part)
{
    constexpr int NT = CIN / 32;
    constexpr int NFRAG = COUTP / 64;
    constexpr int INSTS = CIN / 8;
    constexpr int Q = INSTS / 4;
    constexpr int R = NT * NFRAG;
    constexpr int UPNS = (CIN == 64) ? 4 : 5;
    constexpr int UNITS = 16 << UPNS;
    __shared__ unsigned short raw[RING * 64 * CIN];
    __shared__ unsigned short agg[2][16][CIN + 8];
    __shared__ int   iL[25 * 64];
    __shared__ float wL[25 * 48];
    const int tid = threadIdx.x;
    const int n0 = blockIdx.x * 16;

    for (int q = tid; q < 16 * 75; q += 256) {
        const int node = q / 75, f = q - node * 75;
        const int k = f / 3, v = f - k * 3;
        const int n = n0 + node;
        const bool ok = n < NN;
        const int g = ok ? (n * 75 + f) : 0;
        iL[k * 64 + node * 4 + v] = ok ? idx[g] : 0;
        wL[k * 48 + node * 3 + v] = ok ? wgt[g] : 0.f;
    }
    for (int q = tid; q < 25 * 16; q += 256)
        iL[(q / 16) * 64 + (q - (q / 16) * 16) * 4 + 3] = 0;
    __syncthreads();

    const int wv = tid >> 6;
    const int lane = tid & 63;
    const int l15 = lane & 15;
    const int kg = lane >> 4;
    const int colbase = wv * NFRAG * 16;

    auto issue = [&](int sd) {
        const int base = (sd & (RING - 1)) * (64 * CIN);
        #pragma unroll
        for (int jj = 0; jj < Q; jj++) {
            const int j = wv * Q + jj;
            int row, p;
            if constexpr (CIN == 64) { row = j * 8 + (lane >> 3); p = lane & 7; }
            else                     { row = j * 4 + (lane >> 4); p = lane & 15; }
            const int id = iL[sd * 64 + row];
            gl_lds16(X + (size_t)id * CIN + p * 8, &raw[base + j * 512]);
        }
    };
    auto loadB = [&](int sp, s8v* dst) {
        #pragma unroll
        for (int t = 0; t < NT; t++)
            #pragma unroll
            for (int j = 0; j < NFRAG; j++)
                dst[t * NFRAG + j] = *(const s8v*)(Wt +
                    ((size_t)(sp * (CIN / 8) + t * 4 + kg) * COUTP + colbase + j * 16 + l15) * 8);
    };

    f32x4 acc[NFRAG] = {};
    s8v breg[2][R];

    if constexpr (RING == 4) { issue(0); issue(1); loadB(0, breg[0]); issue(2); }
    else                     { issue(0); loadB(0, breg[0]); issue(1); }

    #pragma unroll
    for (int s = 0; s < 25; s++) {
        if (s + 1 < 25) loadB(s + 1, breg[(s + 1) & 1]);
        if constexpr (RING == 4) {
            if (s <= 22)      waitv<2 * Q + 2 * R>();
            else if (s == 23) waitv<Q + 2 * R>();
            else              waitv<R>();
        } else {
            if (s <= 23)      waitv<Q + 2 * R>();
            else              waitv<R>();
        }
        __builtin_amdgcn_s_barrier();
        {
            const int sb = (s & (RING - 1)) * (64 * CIN);
            #pragma unroll
            for (int u = tid; u < UNITS; u += 256) {
                const int node = u >> UPNS;
                const int e4 = u & ((1 << UPNS) - 1);
                const float w0 = wL[s * 48 + node * 3 + 0];
                const float w1 = wL[s * 48 + node * 3 + 1];
                const float w2 = wL[s * 48 + node * 3 + 2];
                const int rb = sb + node * 4 * CIN + e4 * 4;
                const u32x2 A = *(const u32x2*)&raw[rb + 0 * CIN];
                const u32x2 B = *(const u32x2*)&raw[rb + 1 * CIN];
                const u32x2 C = *(const u32x2*)&raw[rb + 2 * CIN];
                const float v0 = w0 * bfu32lo(A[0]) + w1 * bfu32lo(B[0]) + w2 * bfu32lo(C[0]);
                const float v1 = w0 * bfu32hi(A[0]) + w1 * bfu32hi(B[0]) + w2 * bfu32hi(C[0]);
                const float v2 = w0 * bfu32lo(A[1]) + w1 * bfu32lo(B[1]) + w2 * bfu32lo(C[1]);
                const float v3 = w0 * bfu32hi(A[1]) + w1 * bfu32hi(B[1]) + w2 * bfu32hi(C[1]);
                u32x2 o;
                o[0] = cvtpk(v0, v1);
                o[1] = cvtpk(v2, v3);
                *(u32x2*)&agg[s & 1][node][e4 * 4] = o;
            }
        }
        if constexpr (RING == 4) { if (s + 3 < 25) issue(s + 3); }
        lgkm0();
        __builtin_amdgcn_s_barrier();
        if constexpr (RING == 2) {
            if (s + 2 < 25) issue(s + 2);
            __builtin_amdgcn_sched_barrier(0);
        }
        #pragma unroll
        for (int t = 0; t < NT; t++) {
            const s8v a = *(const s8v*)(&agg[s & 1][l15][t * 32 + kg * 8]);
            #pragma unroll
            for (int j = 0; j < NFRAG; j++)
                acc[j] = __builtin_amdgcn_mfma_f32_16x16x32_bf16(
                    a, breg[s & 1][t * NFRAG + j], acc[j], 0, 0, 0);
        }
    }

    bool f32o = false;
    if constexpr (FINAL) f32o = (*flag != 0);
    #pragma unroll
    for (int j = 0; j < NFRAG; j++) {
        const int col = colbase + j * 16 + l15;
        float s = 0.f, s2 = 0.f;
        if (col < COUT) {
            const float bb = bias[col];
            #pragma unroll
            for (int q = 0; q < 4; q++) {
                const int n = n0 + kg * 4 + q;
                if (n < NN) {
                    const float v = acc[j][q] + bb;
                    if constexpr (FINAL) {
                        if (f32o) ((float*)Ob)[(size_t)n * COUT + col] = v;
                        else ((unsigned short*)Ob)[(size_t)n * COUT + col] = f2bf(v);
                    } else {
                        pre[(size_t)n * COUT + col] = v;
                        s += v; s2 += v * v;
                    }
                }
            }
        }
        if constexpr (!FINAL) {
            s  += __shfl_xor(s, 16);  s  += __shfl_xor(s, 32);
            s2 += __shfl_xor(s2, 16); s2 += __shfl_xor(s2, 32);
            if (kg == 0) {
                part[(size_t)blockIdx.x * 2 * COUT + col] = s;
                part[(size_t)blockIdx.x * 2 * COUT + COUT + col] = s2;
            }
        }
    }
}

// ---- stats finalize: ONE block reduces NBLK partials -> scale/shift[2C] ----
template<int C, int NBLK>
__global__ __launch_bounds__(1024) void fin_k(
    const float* __restrict__ part,
    const float* __restrict__ gm,
    const float* __restrict__ bt,
    float* __restrict__ scsh)
{
    constexpr int RG = 1024 / C;
    __shared__ float ls[1024], ls2[1024];
    const int c = threadIdx.x % C;
    const int g = threadIdx.x / C;
    float s = 0.f, s2 = 0.f;
    for (int b = g; b < NBLK; b += RG) {
        s  += part[(size_t)b * 2 * C + c];
        s2 += part[(size_t)b * 2 * C + C + c];
    }
    ls[threadIdx.x] = s; ls2[threadIdx.x] = s2;
    __syncthreads();
    if (threadIdx.x < C) {
        float a = 0.f, a2 = 0.f;
        #pragma unroll
        for (int g2 = 0; g2 < RG; g2++) {
            a  += ls[g2 * C + threadIdx.x];
            a2 += ls2[g2 * C + threadIdx.x];
        }
        const float inv = 1.f / (float)NN;
        float mu = a * inv;
        float var = a2 * inv - mu * mu;
        float scale = gm[threadIdx.x] * rsqrtf(var + 1e-5f);
        scsh[threadIdx.x] = scale;
        scsh[C + threadIdx.x] = bt[threadIdx.x] - mu * scale;
    }
}

// ---- BN apply ----
template<int C>
__global__ __launch_bounds__(256) void bnap_k(
    const float* __restrict__ pre,
    const float* __restrict__ scsh,
    unsigned short* __restrict__ act)
{
    __shared__ float sc[C], sh[C];
    if (threadIdx.x < C) {
        sc[threadIdx.x] = scsh[threadIdx.x];
        sh[threadIdx.x] = scsh[C + threadIdx.x];
    }
    __syncthreads();
    constexpr int TOTAL4 = NN * C / 4;
    const int stride = gridDim.x * 256;
    for (int i = blockIdx.x * 256 + threadIdx.x; i < TOTAL4; i += stride) {
        const f32x4 v = *(const f32x4*)(pre + (size_t)i * 4);
        const int c0 = (i * 4) % C;
        u32x2 o;
        o[0] = cvtpk(fmaxf(v[0] * sc[c0]     + sh[c0],     0.f),
                     fmaxf(v[1] * sc[c0 + 1] + sh[c0 + 1], 0.f));
        o[1] = cvtpk(fmaxf(v[2] * sc[c0 + 2] + sh[c0 + 2], 0.f),
                     fmaxf(v[3] * sc[c0 + 3] + sh[c0 + 3], 0.f));
        *(u32x2*)(act + (size_t)i * 4) = o;
    }
}

extern "C" void kernel_launch(void* const* d_in, const int* in_sizes, int n_in,
                              void* d_out, int out_size, void* d_ws, size_t ws_size,
                              hipStream_t stream) {
    const void* x    = d_in[0];
    const int*  idx  = (const int*)d_in[1];
    const void* wgt  = d_in[2];
    const void* W1   = d_in[3];
    const void* b1   = d_in[4];
    const void* g1   = d_in[5];
    const void* be1  = d_in[6];
    const void* W2   = d_in[7];
    const void* b2   = d_in[8];
    const void* g2   = d_in[9];
    const void* be2  = d_in[10];
    const void* W3   = d_in[11];
    const void* b3   = d_in[12];
    const void* g3   = d_in[13];
    const void* be3  = d_in[14];
    const void* Wout = d_in[15];
    const void* bout = d_in[16];

    char* ws = (char*)d_ws;
    size_t off = 0;
    auto alloc = [&](size_t bytes) {
        off = (off + 255) & ~(size_t)255;
        size_t o = off; off += bytes; return o;
    };
    const size_t o_flag = alloc(4);
    const size_t o_x4   = alloc((size_t)NN * 4 * 2);
    const size_t o_wgtc = alloc((size_t)NN * 75 * 4);
    const size_t o_W1c  = alloc(64 * 80 * 2);
    const size_t o_Wt2  = alloc((size_t)200 * 64 * 8 * 2);
    const size_t o_Wt3  = alloc((size_t)200 * 128 * 8 * 2);
    const size_t o_Wt4  = alloc((size_t)400 * 64 * 8 * 2);
    const size_t o_bias = alloc(1024 * 4);
    const size_t o_pre  = alloc((size_t)NN * 128 * 4);
    const size_t o_actA = alloc((size_t)NN * 128 * 2);
    const size_t o_actB = alloc((size_t)NN * 64 * 2);
    const size_t o_part = alloc((size_t)641 * 2 * 128 * 4);
    const size_t o_scsh = alloc(2 * 128 * 4);
    if (ws_size < off) return;

    int* flag = (int*)(ws + o_flag);
    unsigned short* x4  = (unsigned short*)(ws + o_x4);
    float* wgtc = (float*)(ws + o_wgtc);
    unsigned short* W1c = (unsigned short*)(ws + o_W1c);
    unsigned short* Wt2 = (unsigned short*)(ws + o_Wt2);
    unsigned short* Wt3 = (unsigned short*)(ws + o_Wt3);
    unsigned short* Wt4 = (unsigned short*)(ws + o_Wt4);
    float* biasc = (float*)(ws + o_bias);
    float* pre  = (float*)(ws + o_pre);
    unsigned short* actA = (unsigned short*)(ws + o_actA);
    unsigned short* actB = (unsigned short*)(ws + o_actB);
    float* part = (float*)(ws + o_part);
    float* scsh = (float*)(ws + o_scsh);

    detect_k<<<1, 64, 0, stream>>>(wgt, flag);

    Tab t;
    t.s[0]  = { x,    x4,   NN * 4,         NN * 3,  4, 0, 0, 0 };
    t.s[1]  = { wgt,  wgtc, NN * 75,        NN * 75, 1, 0, 0, 0 };
    t.s[2]  = { W1,   W1c,  64 * 80,        64 * 80, 2, 0, 0, 0 };
    t.s[3]  = { W2,   Wt2,  200 * 64 * 8,   0,       3, 1600, 64, 64 };
    t.s[4]  = { W3,   Wt3,  200 * 128 * 8,  0,       3, 1600, 128, 128 };
    t.s[5]  = { Wout, Wt4,  400 * 64 * 8,   0,       3, 3200, 36, 64 };
    t.s[6]  = { b1,   biasc + 0,   64, 64, 1, 0, 0, 0 };
    t.s[7]  = { g1,   biasc + 64,  64, 64, 1, 0, 0, 0 };
    t.s[8]  = { be1,  biasc + 128, 64, 64, 1, 0, 0, 0 };
    t.s[9]  = { b2,   biasc + 192, 64, 64, 1, 0, 0, 0 };
    t.s[10] = { g2,   biasc + 256, 64, 64, 1, 0, 0, 0 };
    t.s[11] = { be2,  biasc + 320, 64, 64, 1, 0, 0, 0 };
    t.s[12] = { b3,   biasc + 384, 128, 128, 1, 0, 0, 0 };
    t.s[13] = { g3,   biasc + 512, 128, 128, 1, 0, 0, 0 };
    t.s[14] = { be3,  biasc + 640, 128, 128, 1, 0, 0, 0 };
    t.s[15] = { bout, biasc + 768, 36, 36, 1, 0, 0, 0 };
    canon_k<<<dim3(768, 16), 256, 0, stream>>>(t, flag);

    dim3 B(256);
    // layer 1: 3 -> 64 (VALU, vectorized gather, fused stats)
    conv1_k<4, 64, 64, 16><<<641, B, 0, stream>>>(x4, idx, wgtc, W1c, biasc + 0, pre, part);
    fin_k<64, 641><<<1, 1024, 0, stream>>>(part, biasc + 64, biasc + 128, scsh);
    bnap_k<64><<<512, B, 0, stream>>>(pre, scsh, actA);
    // layer 2: 64 -> 64 (grouped DMA, swizzled)
    convg_k<64, 64><<<641, B, 0, stream>>>(actA, idx, wgtc, Wt2, biasc + 192, pre, part);
    fin_k<64, 641><<<1, 1024, 0, stream>>>(part, biasc + 256, biasc + 320, scsh);
    bnap_k<64><<<512, B, 0, stream>>>(pre, scsh, actB);
    // layer 3: 64 -> 128 (grouped DMA, swizzled)
    convg_k<128, 128><<<641, B, 0, stream>>>(actB, idx, wgtc, Wt3, biasc + 384, pre, part);
    fin_k<128, 641><<<1, 1024, 0, stream>>>(part, biasc + 512, biasc + 640, scsh);
    bnap_k<128><<<512, B, 0, stream>>>(pre, scsh, actA);
    // layer 4: 128 -> 36 (COUTP=64, ring-2), direct to d_out
    convdma2_k<128, 64, 36, 2, true><<<641, B, 0, stream>>>(
        actA, idx, wgtc, Wt4, biasc + 768, nullptr, d_out, flag, nullptr);
}

// Round 18
// 157.163 us; speedup vs baseline: 3.9110x; 1.0043x over previous
//
#include <hip/hip_runtime.h>

#define NN 10242

typedef short s8v __attribute__((ext_vector_type(8)));
typedef unsigned int u32x2 __attribute__((ext_vector_type(2)));
typedef float f32x4 __attribute__((ext_vector_type(4)));

static __device__ __forceinline__ float bf2f(unsigned short u) {
    unsigned int i = ((unsigned int)u) << 16;
    return __builtin_bit_cast(float, i);
}
static __device__ __forceinline__ float bfu32lo(unsigned int d) {
    return __builtin_bit_cast(float, d << 16);
}
static __device__ __forceinline__ float bfu32hi(unsigned int d) {
    return __builtin_bit_cast(float, d & 0xffff0000u);
}
static __device__ __forceinline__ unsigned short f2bf(float f) {
    unsigned int i = __builtin_bit_cast(unsigned int, f);
    unsigned int lsb = (i >> 16) & 1u;
    i += 0x7fffu + lsb;
    return (unsigned short)(i >> 16);
}
static __device__ __forceinline__ unsigned int cvtpk(float lo, float hi) {
    unsigned int r;
    asm("v_cvt_pk_bf16_f32 %0, %1, %2" : "=v"(r) : "v"(lo), "v"(hi));
    return r;
}
static __device__ __forceinline__ void gl_lds16(const unsigned short* g, unsigned short* l) {
    __builtin_amdgcn_global_load_lds(
        (const __attribute__((address_space(1))) unsigned int*)g,
        (__attribute__((address_space(3))) unsigned int*)l, 16, 0, 0);
}
template<int N> static __device__ __forceinline__ void waitv() {
    asm volatile("s_waitcnt vmcnt(%0)" :: "n"(N) : "memory");
    __builtin_amdgcn_sched_barrier(0);
}
static __device__ __forceinline__ void lgkm0() {
    asm volatile("s_waitcnt lgkmcnt(0)" ::: "memory");
    __builtin_amdgcn_sched_barrier(0);
}
static __device__ __forceinline__ int imin(int a, int b) { return a < b ? a : b; }

// ---- dtype detector ----
__global__ void detect_k(const void* __restrict__ wgt, int* __restrict__ flag) {
    const float* wf = (const float*)wgt;
    const int r = threadIdx.x;
    float s = wf[3 * r] + wf[3 * r + 1] + wf[3 * r + 2];
    bool ok = (s == s) && (fabsf(s - 1.f) < 0.05f);
    unsigned long long m = __ballot(ok);
    if (r == 0) *flag = (__popcll(m) >= 60) ? 1 : 0;
}

// ---- canonicalizer ----
struct Seg { const void* src; void* dst; int n; int nsrc; int mode; int K; int cout; int cpad; };
struct Tab { Seg s[16]; };

__global__ __launch_bounds__(256) void canon_k(Tab t, const int* __restrict__ flag) {
    const Seg sg = t.s[blockIdx.y];
    const bool f32src = (*flag != 0);
    for (int i = blockIdx.x * 256 + threadIdx.x; i < sg.n; i += gridDim.x * 256) {
        if (sg.mode == 0) {
            unsigned short v = 0;
            if (i < sg.nsrc)
                v = f32src ? f2bf(((const float*)sg.src)[i])
                           : ((const unsigned short*)sg.src)[i];
            ((unsigned short*)sg.dst)[i] = v;
        } else if (sg.mode == 1) {
            float v = f32src ? ((const float*)sg.src)[i]
                             : bf2f(((const unsigned short*)sg.src)[i]);
            ((float*)sg.dst)[i] = v;
        } else if (sg.mode == 2) {
            const int row = i / 80, col = i - row * 80;
            unsigned short v = 0;
            if (col < 75) {
                const int j = row * 75 + col;
                v = f32src ? f2bf(((const float*)sg.src)[j])
                           : ((const unsigned short*)sg.src)[j];
            }
            ((unsigned short*)sg.dst)[i] = v;
        } else if (sg.mode == 3) {
            const int e = i & 7;
            const int r = i >> 3;
            const int c = r % sg.cpad;
            const int k8 = r / sg.cpad;
            unsigned short v = 0;
            if (c < sg.cout) {
                const int j = c * sg.K + k8 * 8 + e;
                v = f32src ? f2bf(((const float*)sg.src)[j])
                           : ((const unsigned short*)sg.src)[j];
            }
            ((unsigned short*)sg.dst)[i] = v;
        } else {
            const int row = i >> 2, col = i & 3;
            unsigned short v = 0;
            if (col < 3) {
                const int j = row * 3 + col;
                v = f32src ? f2bf(((const float*)sg.src)[j])
                           : ((const unsigned short*)sg.src)[j];
            }
            ((unsigned short*)sg.dst)[i] = v;
        }
    }
}

// ---- layer-1 conv (K=80, VALU) + fused per-block stats partials ----
template<int CIN4, int COUT, int CG, int NB>
__global__ __launch_bounds__(256) void conv1_k(
    const unsigned short* __restrict__ X4,
    const int* __restrict__ idx,
    const float* __restrict__ wgt,
    const unsigned short* __restrict__ W,
    const float* __restrict__ bias,
    float* __restrict__ Of,
    float* __restrict__ part)
{
    constexpr int K = 75;
    constexpr int KPAD = 80;
    __shared__ unsigned short agg[NB][KPAD];
    __shared__ float ls[256], ls2[256];
    const int tid = threadIdx.x;
    const int n0 = blockIdx.x * NB;

    for (int p = tid; p < NB * 25; p += 256) {
        const int r = p / 25;
        const int k = p - r * 25;
        const int n = n0 + r;
        if (n < NN) {
            const int base = n * 75 + k * 3;
            const int i0 = idx[base], i1 = idx[base + 1], i2 = idx[base + 2];
            const float w0 = wgt[base], w1 = wgt[base + 1], w2 = wgt[base + 2];
            const unsigned long long A = *(const unsigned long long*)(X4 + (size_t)i0 * 4);
            const unsigned long long B = *(const unsigned long long*)(X4 + (size_t)i1 * 4);
            const unsigned long long C = *(const unsigned long long*)(X4 + (size_t)i2 * 4);
            #pragma unroll
            for (int e = 0; e < 3; e++) {
                float v = w0 * bf2f((unsigned short)(A >> (16 * e))) +
                          w1 * bf2f((unsigned short)(B >> (16 * e))) +
                          w2 * bf2f((unsigned short)(C >> (16 * e)));
                agg[r][k * 3 + e] = f2bf(v);
            }
        } else {
            #pragma unroll
            for (int e = 0; e < 3; e++) agg[r][k * 3 + e] = 0;
        }
    }
    for (int p = tid; p < NB * (KPAD - K); p += 256) {
        const int r = p / (KPAD - K);
        agg[r][K + p - r * (KPAD - K)] = 0;
    }
    __syncthreads();

    constexpr int RG = 256 / CG;
    constexpr int RPT = NB / RG;
    const int c = tid % CG;
    const int rq = tid / CG;
    float acc[RPT] = {};
    const unsigned short* Wr = W + (size_t)c * KPAD;
    for (int j = 0; j < KPAD; j += 8) {
        s8v wv = *(const s8v*)(Wr + j);
        float wf[8];
        #pragma unroll
        for (int q = 0; q < 8; q++) wf[q] = bf2f((unsigned short)wv[q]);
        #pragma unroll
        for (int rr = 0; rr < RPT; rr++) {
            s8v av = *(const s8v*)(&agg[rq * RPT + rr][j]);
            #pragma unroll
            for (int q = 0; q < 8; q++)
                acc[rr] += wf[q] * bf2f((unsigned short)av[q]);
        }
    }
    const float bb = bias[c];
    float s = 0.f, s2 = 0.f;
    #pragma unroll
    for (int rr = 0; rr < RPT; rr++) {
        const int n = n0 + rq * RPT + rr;
        if (n < NN) {
            const float v = acc[rr] + bb;
            Of[(size_t)n * COUT + c] = v;
            s += v; s2 += v * v;
        }
    }
    ls[tid] = s; ls2[tid] = s2;
    __syncthreads();
    if (tid < COUT) {
        float a = 0.f, a2 = 0.f;
        #pragma unroll
        for (int g2 = 0; g2 < RG; g2++) {
            a  += ls[g2 * CG + tid];
            a2 += ls2[g2 * CG + tid];
        }
        part[(size_t)blockIdx.x * 2 * COUT + tid] = a;
        part[(size_t)blockIdx.x * 2 * COUT + COUT + tid] = a2;
    }
}

// ---- grouped DMA conv (CIN=64, ring-4, 2 slots/iteration, XOR-swizzled raw) ----
template<int COUTP, int COUT>
__global__ __launch_bounds__(256, 3) void convg_k(
    const unsigned short* __restrict__ X,
    const int* __restrict__ idx,
    const float* __restrict__ wgt,
    const unsigned short* __restrict__ Wt,   // [200][COUTP][8]
    const float* __restrict__ bias,
    float* __restrict__ pre,
    float* __restrict__ part)
{
    constexpr int CIN = 64;
    constexpr int NT = 2;
    constexpr int NFRAG = COUTP / 64;
    constexpr int Q = 2;
    constexpr int R = NT * NFRAG;
    __shared__ unsigned short raw[4 * 64 * CIN];
    __shared__ unsigned short agg[2][16][CIN + 8];
    __shared__ unsigned short iL[25 * 64];
    __shared__ float wL[25 * 48];
    const int tid = threadIdx.x;
    const int n0 = blockIdx.x * 16;

    for (int q = tid; q < 16 * 75; q += 256) {
        const int node = q / 75, f = q - node * 75;
        const int k = f / 3, v = f - k * 3;
        const int n = n0 + node;
        const bool ok = n < NN;
        const int g = ok ? (n * 75 + f) : 0;
        iL[k * 64 + node * 4 + v] = ok ? (unsigned short)idx[g] : 0;
        wL[k * 48 + node * 3 + v] = ok ? wgt[g] : 0.f;
    }
    for (int q = tid; q < 25 * 16; q += 256)
        iL[(q / 16) * 64 + (q - (q / 16) * 16) * 4 + 3] = 0;
    __syncthreads();

    const int wv = tid >> 6;
    const int lane = tid & 63;
    const int l15 = lane & 15;
    const int kg = lane >> 4;
    const int colbase = wv * NFRAG * 16;

    auto issue = [&](int sd) {
        const int base = (sd & 3) * (64 * CIN);
        #pragma unroll
        for (int jj = 0; jj < Q; jj++) {
            const int j = wv * Q + jj;
            const int row = j * 8 + (lane >> 3);
            const int p = lane & 7;
            const int ch = p ^ ((row >> 2) & 7);
            const int id = (int)iL[sd * 64 + row];
            gl_lds16(X + (size_t)id * CIN + ch * 8, &raw[base + j * 512]);
        }
    };
    auto loadB = [&](int sp, s8v* dst) {
        #pragma unroll
        for (int t = 0; t < NT; t++)
            #pragma unroll
            for (int j = 0; j < NFRAG; j++)
                dst[t * NFRAG + j] = *(const s8v*)(Wt +
                    ((size_t)(sp * 8 + t * 4 + kg) * COUTP + colbase + j * 16 + l15) * 8);
    };
    auto interp = [&](int s, int par) {
        const int sb = (s & 3) * (64 * CIN);
        const int node = tid >> 4;
        const int e4 = tid & 15;
        const float w0 = wL[s * 48 + node * 3 + 0];
        const float w1 = wL[s * 48 + node * 3 + 1];
        const float w2 = wL[s * 48 + node * 3 + 2];
        const int chunk = (e4 >> 1) ^ (node & 7);
        const int off = chunk * 8 + (e4 & 1) * 4;
        const int rb = sb + node * 4 * CIN + off;
        const u32x2 A = *(const u32x2*)&raw[rb + 0 * CIN];
        const u32x2 B = *(const u32x2*)&raw[rb + 1 * CIN];
        const u32x2 C = *(const u32x2*)&raw[rb + 2 * CIN];
        const float v0 = w0 * bfu32lo(A[0]) + w1 * bfu32lo(B[0]) + w2 * bfu32lo(C[0]);
        const float v1 = w0 * bfu32hi(A[0]) + w1 * bfu32hi(B[0]) + w2 * bfu32hi(C[0]);
        const float v2 = w0 * bfu32lo(A[1]) + w1 * bfu32lo(B[1]) + w2 * bfu32lo(C[1]);
        const float v3 = w0 * bfu32hi(A[1]) + w1 * bfu32hi(B[1]) + w2 * bfu32hi(C[1]);
        u32x2 o;
        o[0] = cvtpk(v0, v1);
        o[1] = cvtpk(v2, v3);
        *(u32x2*)&agg[par][node][e4 * 4] = o;
    };

    f32x4 acc[NFRAG] = {};
    s8v breg[2][2][R];

    issue(0); issue(1);
    loadB(0, breg[0][0]); loadB(1, breg[0][1]);
    issue(2); issue(3);

    #pragma unroll
    for (int g = 0; g < 12; g++) {
        const int s0 = 2 * g, s1 = 2 * g + 1;
        if (g < 11) { loadB(s0 + 2, breg[(g + 1) & 1][0]); loadB(s0 + 3, breg[(g + 1) & 1][1]); }
        else        { loadB(24, breg[(g + 1) & 1][0]); }
        if (g <= 10) waitv<2 * Q + 2 * R>(); else waitv<Q + R>();
        __builtin_amdgcn_s_barrier();
        interp(s0, 0);
        interp(s1, 1);
        lgkm0();
        __builtin_amdgcn_s_barrier();
        if (s0 + 4 < 25) issue(s0 + 4);
        if (s0 + 5 < 25) issue(s0 + 5);
        __builtin_amdgcn_sched_barrier(0);
        #pragma unroll
        for (int t = 0; t < NT; t++) {
            const s8v a0 = *(const s8v*)(&agg[0][l15][t * 32 + kg * 8]);
            #pragma unroll
            for (int j = 0; j < NFRAG; j++)
                acc[j] = __builtin_amdgcn_mfma_f32_16x16x32_bf16(
                    a0, breg[g & 1][0][t * NFRAG + j], acc[j], 0, 0, 0);
        }
        #pragma unroll
        for (int t = 0; t < NT; t++) {
            const s8v a1 = *(const s8v*)(&agg[1][l15][t * 32 + kg * 8]);
            #pragma unroll
            for (int j = 0; j < NFRAG; j++)
                acc[j] = __builtin_amdgcn_mfma_f32_16x16x32_bf16(
                    a1, breg[g & 1][1][t * NFRAG + j], acc[j], 0, 0, 0);
        }
    }
    waitv<0>();
    __builtin_amdgcn_s_barrier();
    interp(24, 0);
    lgkm0();
    __builtin_amdgcn_s_barrier();
    #pragma unroll
    for (int t = 0; t < NT; t++) {
        const s8v a = *(const s8v*)(&agg[0][l15][t * 32 + kg * 8]);
        #pragma unroll
        for (int j = 0; j < NFRAG; j++)
            acc[j] = __builtin_amdgcn_mfma_f32_16x16x32_bf16(
                a, breg[0][0][t * NFRAG + j], acc[j], 0, 0, 0);
    }

    #pragma unroll
    for (int j = 0; j < NFRAG; j++) {
        const int col = colbase + j * 16 + l15;
        float s = 0.f, s2 = 0.f;
        const float bb = bias[col];
        #pragma unroll
        for (int q = 0; q < 4; q++) {
            const int n = n0 + kg * 4 + q;
            if (n < NN) {
                const float v = acc[j][q] + bb;
                pre[(size_t)n * COUT + col] = v;
                s += v; s2 += v * v;
            }
        }
        s  += __shfl_xor(s, 16);  s  += __shfl_xor(s, 32);
        s2 += __shfl_xor(s2, 16); s2 += __shfl_xor(s2, 32);
        if (kg == 0) {
            part[(size_t)blockIdx.x * 2 * COUT + col] = s;
            part[(size_t)blockIdx.x * 2 * COUT + COUT + col] = s2;
        }
    }
}

// ---- layer-4 conv: CIN=128 as 50 half-slots of 64ch; ring-4, swizzled ----
// unit u: slot s=u>>1, channel half h=u&1. Output 36 cols (COUTP=64 pad).
__global__ __launch_bounds__(256, 3) void conv4_k(
    const unsigned short* __restrict__ X,    // [NN][128] bf16
    const int* __restrict__ idx,
    const float* __restrict__ wgt,
    const unsigned short* __restrict__ Wt,   // [400][64][8]
    const float* __restrict__ bias,
    void* __restrict__ Ob,
    const int* __restrict__ flag)
{
    constexpr int COUTP = 64;
    constexpr int COUT = 36;
    constexpr int NT = 2;
    constexpr int Q = 2;
    constexpr int R = 2;                     // NT * NFRAG(=1)
    __shared__ unsigned short raw[4 * 64 * 64];
    __shared__ unsigned short agg[2][16][72];
    __shared__ unsigned short iL[25 * 64];
    __shared__ float wL[25 * 48];
    const int tid = threadIdx.x;
    const int n0 = blockIdx.x * 16;

    for (int q = tid; q < 16 * 75; q += 256) {
        const int node = q / 75, f = q - node * 75;
        const int k = f / 3, v = f - k * 3;
        const int n = n0 + node;
        const bool ok = n < NN;
        const int g = ok ? (n * 75 + f) : 0;
        iL[k * 64 + node * 4 + v] = ok ? (unsigned short)idx[g] : 0;
        wL[k * 48 + node * 3 + v] = ok ? wgt[g] : 0.f;
    }
    for (int q = tid; q < 25 * 16; q += 256)
        iL[(q / 16) * 64 + (q - (q / 16) * 16) * 4 + 3] = 0;
    __syncthreads();

    const int wv = tid >> 6;
    const int lane = tid & 63;
    const int l15 = lane & 15;
    const int kg = lane >> 4;
    const int colbase = wv * 16;

    // unit u: 64 rows x 64ch (half h=u&1); source chunk XOR-swizzled by node
    auto issue = [&](int u) {
        const int base = (u & 3) * (64 * 64);
        const int s = u >> 1, h = u & 1;
        #pragma unroll
        for (int jj = 0; jj < Q; jj++) {
            const int j = wv * Q + jj;
            const int row = j * 8 + (lane >> 3);
            const int p = lane & 7;
            const int ch = p ^ ((row >> 2) & 7);
            const int id = (int)iL[s * 64 + row];
            gl_lds16(X + (size_t)id * 128 + h * 64 + ch * 8, &raw[base + j * 512]);
        }
    };
    auto loadB = [&](int u, s8v* dst) {
        #pragma unroll
        for (int t = 0; t < NT; t++)
            dst[t] = *(const s8v*)(Wt +
                ((size_t)(u * 8 + t * 4 + kg) * COUTP + colbase + l15) * 8);
    };
    auto interp = [&](int u, int par) {
        const int sb = (u & 3) * (64 * 64);
        const int s = u >> 1;
        const int node = tid >> 4;
        const int e4 = tid & 15;
        const float w0 = wL[s * 48 + node * 3 + 0];
        const float w1 = wL[s * 48 + node * 3 + 1];
        const float w2 = wL[s * 48 + node * 3 + 2];
        const int chunk = (e4 >> 1) ^ (node & 7);
        const int off = chunk * 8 + (e4 & 1) * 4;
        const int rb = sb + node * 4 * 64 + off;
        const u32x2 A = *(const u32x2*)&raw[rb + 0 * 64];
        const u32x2 B = *(const u32x2*)&raw[rb + 1 * 64];
        const u32x2 C = *(const u32x2*)&raw[rb + 2 * 64];
        const float v0 = w0 * bfu32lo(A[0]) + w1 * bfu32lo(B[0]) + w2 * bfu32lo(C[0]);
        const float v1 = w0 * bfu32hi(A[0]) + w1 * bfu32hi(B[0]) + w2 * bfu32hi(C[0]);
        const float v2 = w0 * bfu32lo(A[1]) + w1 * bfu32lo(B[1]) + w2 * bfu32lo(C[1]);
        const float v3 = w0 * bfu32hi(A[1]) + w1 * bfu32hi(B[1]) + w2 * bfu32hi(C[1]);
        u32x2 o;
        o[0] = cvtpk(v0, v1);
        o[1] = cvtpk(v2, v3);
        *(u32x2*)&agg[par][node][e4 * 4] = o;
    };

    f32x4 acc = {};
    s8v breg[2][2][R];

    issue(0); issue(1);
    loadB(0, breg[0][0]); loadB(1, breg[0][1]);
    issue(2); issue(3);

    #pragma unroll
    for (int g = 0; g < 25; g++) {
        const int u0 = 2 * g, u1 = 2 * g + 1;
        if (g < 24) { loadB(u0 + 2, breg[(g + 1) & 1][0]); loadB(u0 + 3, breg[(g + 1) & 1][1]); }
        if (g <= 23) waitv<2 * Q + 2 * R>(); else waitv<0>();
        __builtin_amdgcn_s_barrier();
        interp(u0, 0);
        interp(u1, 1);
        lgkm0();
        __builtin_amdgcn_s_barrier();
        if (u0 + 4 < 50) issue(u0 + 4);
        if (u0 + 5 < 50) issue(u0 + 5);
        __builtin_amdgcn_sched_barrier(0);
        #pragma unroll
        for (int t = 0; t < NT; t++) {
            const s8v a0 = *(const s8v*)(&agg[0][l15][t * 32 + kg * 8]);
            acc = __builtin_amdgcn_mfma_f32_16x16x32_bf16(a0, breg[g & 1][0][t], acc, 0, 0, 0);
        }
        #pragma unroll
        for (int t = 0; t < NT; t++) {
            const s8v a1 = *(const s8v*)(&agg[1][l15][t * 32 + kg * 8]);
            acc = __builtin_amdgcn_mfma_f32_16x16x32_bf16(a1, breg[g & 1][1][t], acc, 0, 0, 0);
        }
    }

    const bool f32o = (*flag != 0);
    const int col = colbase + l15;
    if (col < COUT) {
        const float bb = bias[col];
        #pragma unroll
        for (int q = 0; q < 4; q++) {
            const int n = n0 + kg * 4 + q;           // C row = (lane>>4)*4 + reg
            if (n < NN) {
                const float v = acc[q] + bb;
                if (f32o) ((float*)Ob)[(size_t)n * COUT + col] = v;
                else      ((unsigned short*)Ob)[(size_t)n * COUT + col] = f2bf(v);
            }
        }
    }
}

// ---- stats finalize: ONE block reduces NBLK partials -> scale/shift[2C] ----
template<int C, int NBLK>
__global__ __launch_bounds__(1024) void fin_k(
    const float* __restrict__ part,
    const float* __restrict__ gm,
    const float* __restrict__ bt,
    float* __restrict__ scsh)
{
    constexpr int RG = 1024 / C;
    __shared__ float ls[1024], ls2[1024];
    const int c = threadIdx.x % C;
    const int g = threadIdx.x / C;
    float s = 0.f, s2 = 0.f;
    for (int b = g; b < NBLK; b += RG) {
        s  += part[(size_t)b * 2 * C + c];
        s2 += part[(size_t)b * 2 * C + C + c];
    }
    ls[threadIdx.x] = s; ls2[threadIdx.x] = s2;
    __syncthreads();
    if (threadIdx.x < C) {
        float a = 0.f, a2 = 0.f;
        #pragma unroll
        for (int g2 = 0; g2 < RG; g2++) {
            a  += ls[g2 * C + threadIdx.x];
            a2 += ls2[g2 * C + threadIdx.x];
        }
        const float inv = 1.f / (float)NN;
        float mu = a * inv;
        float var = a2 * inv - mu * mu;
        float scale = gm[threadIdx.x] * rsqrtf(var + 1e-5f);
        scsh[threadIdx.x] = scale;
        scsh[C + threadIdx.x] = bt[threadIdx.x] - mu * scale;
    }
}

// ---- BN apply ----
template<int C>
__global__ __launch_bounds__(256) void bnap_k(
    const float* __restrict__ pre,
    const float* __restrict__ scsh,
    unsigned short* __restrict__ act)
{
    __shared__ float sc[C], sh[C];
    if (threadIdx.x < C) {
        sc[threadIdx.x] = scsh[threadIdx.x];
        sh[threadIdx.x] = scsh[C + threadIdx.x];
    }
    __syncthreads();
    constexpr int TOTAL4 = NN * C / 4;
    const int stride = gridDim.x * 256;
    for (int i = blockIdx.x * 256 + threadIdx.x; i < TOTAL4; i += stride) {
        const f32x4 v = *(const f32x4*)(pre + (size_t)i * 4);
        const int c0 = (i * 4) % C;
        u32x2 o;
        o[0] = cvtpk(fmaxf(v[0] * sc[c0]     + sh[c0],     0.f),
                     fmaxf(v[1] * sc[c0 + 1] + sh[c0 + 1], 0.f));
        o[1] = cvtpk(fmaxf(v[2] * sc[c0 + 2] + sh[c0 + 2], 0.f),
                     fmaxf(v[3] * sc[c0 + 3] + sh[c0 + 3], 0.f));
        *(u32x2*)(act + (size_t)i * 4) = o;
    }
}

extern "C" void kernel_launch(void* const* d_in, const int* in_sizes, int n_in,
                              void* d_out, int out_size, void* d_ws, size_t ws_size,
                              hipStream_t stream) {
    const void* x    = d_in[0];
    const int*  idx  = (const int*)d_in[1];
    const void* wgt  = d_in[2];
    const void* W1   = d_in[3];
    const void* b1   = d_in[4];
    const void* g1   = d_in[5];
    const void* be1  = d_in[6];
    const void* W2   = d_in[7];
    const void* b2   = d_in[8];
    const void* g2   = d_in[9];
    const void* be2  = d_in[10];
    const void* W3   = d_in[11];
    const void* b3   = d_in[12];
    const void* g3   = d_in[13];
    const void* be3  = d_in[14];
    const void* Wout = d_in[15];
    const void* bout = d_in[16];

    char* ws = (char*)d_ws;
    size_t off = 0;
    auto alloc = [&](size_t bytes) {
        off = (off + 255) & ~(size_t)255;
        size_t o = off; off += bytes; return o;
    };
    const size_t o_flag = alloc(4);
    const size_t o_x4   = alloc((size_t)NN * 4 * 2);
    const size_t o_wgtc = alloc((size_t)NN * 75 * 4);
    const size_t o_W1c  = alloc(64 * 80 * 2);
    const size_t o_Wt2  = alloc((size_t)200 * 64 * 8 * 2);
    const size_t o_Wt3  = alloc((size_t)200 * 128 * 8 * 2);
    const size_t o_Wt4  = alloc((size_t)400 * 64 * 8 * 2);
    const size_t o_bias = alloc(1024 * 4);
    const size_t o_pre  = alloc((size_t)NN * 128 * 4);
    const size_t o_actA = alloc((size_t)NN * 128 * 2);
    const size_t o_actB = alloc((size_t)NN * 64 * 2);
    const size_t o_part = alloc((size_t)641 * 2 * 128 * 4);
    const size_t o_scsh = alloc(2 * 128 * 4);
    if (ws_size < off) return;

    int* flag = (int*)(ws + o_flag);
    unsigned short* x4  = (unsigned short*)(ws + o_x4);
    float* wgtc = (float*)(ws + o_wgtc);
    unsigned short* W1c = (unsigned short*)(ws + o_W1c);
    unsigned short* Wt2 = (unsigned short*)(ws + o_Wt2);
    unsigned short* Wt3 = (unsigned short*)(ws + o_Wt3);
    unsigned short* Wt4 = (unsigned short*)(ws + o_Wt4);
    float* biasc = (float*)(ws + o_bias);
    float* pre  = (float*)(ws + o_pre);
    unsigned short* actA = (unsigned short*)(ws + o_actA);
    unsigned short* actB = (unsigned short*)(ws + o_actB);
    float* part = (float*)(ws + o_part);
    float* scsh = (float*)(ws + o_scsh);

    detect_k<<<1, 64, 0, stream>>>(wgt, flag);

    Tab t;
    t.s[0]  = { x,    x4,   NN * 4,         NN * 3,  4, 0, 0, 0 };
    t.s[1]  = { wgt,  wgtc, NN * 75,        NN * 75, 1, 0, 0, 0 };
    t.s[2]  = { W1,   W1c,  64 * 80,        64 * 80, 2, 0, 0, 0 };
    t.s[3]  = { W2,   Wt2,  200 * 64 * 8,   0,       3, 1600, 64, 64 };
    t.s[4]  = { W3,   Wt3,  200 * 128 * 8,  0,       3, 1600, 128, 128 };
    t.s[5]  = { Wout, Wt4,  400 * 64 * 8,   0,       3, 3200, 36, 64 };
    t.s[6]  = { b1,   biasc + 0,   64, 64, 1, 0, 0, 0 };
    t.s[7]  = { g1,   biasc + 64,  64, 64, 1, 0, 0, 0 };
    t.s[8]  = { be1,  biasc + 128, 64, 64, 1, 0, 0, 0 };
    t.s[9]  = { b2,   biasc + 192, 64, 64, 1, 0, 0, 0 };
    t.s[10] = { g2,   biasc + 256, 64, 64, 1, 0, 0, 0 };
    t.s[11] = { be2,  biasc + 320, 64, 64, 1, 0, 0, 0 };
    t.s[12] = { b3,   biasc + 384, 128, 128, 1, 0, 0, 0 };
    t.s[13] = { g3,   biasc + 512, 128, 128, 1, 0, 0, 0 };
    t.s[14] = { be3,  biasc + 640, 128, 128, 1, 0, 0, 0 };
    t.s[15] = { bout, biasc + 768, 36, 36, 1, 0, 0, 0 };
    canon_k<<<dim3(768, 16), 256, 0, stream>>>(t, flag);

    dim3 B(256);
    // layer 1: 3 -> 64 (VALU, vectorized gather, fused stats)
    conv1_k<4, 64, 64, 16><<<641, B, 0, stream>>>(x4, idx, wgtc, W1c, biasc + 0, pre, part);
    fin_k<64, 641><<<1, 1024, 0, stream>>>(part, biasc + 64, biasc + 128, scsh);
    bnap_k<64><<<512, B, 0, stream>>>(pre, scsh, actA);
    // layer 2: 64 -> 64 (grouped DMA, swizzled)
    convg_k<64, 64><<<641, B, 0, stream>>>(actA, idx, wgtc, Wt2, biasc + 192, pre, part);
    fin_k<64, 641><<<1, 1024, 0, stream>>>(part, biasc + 256, biasc + 320, scsh);
    bnap_k<64><<<512, B, 0, stream>>>(pre, scsh, actB);
    // layer 3: 64 -> 128 (grouped DMA, swizzled)
    convg_k<128, 128><<<641, B, 0, stream>>>(actB, idx, wgtc, Wt3, biasc + 384, pre, part);
    fin_k<128, 641><<<1, 1024, 0, stream>>>(part, biasc + 512, biasc + 640, scsh);
    bnap_k<128><<<512, B, 0, stream>>>(pre, scsh, actA);
    // layer 4: 128 -> 36 via 50 half-slots (ring-4, swizzled), direct to d_out
    conv4_k<<<641, B, 0, stream>>>(actA, idx, wgtc, Wt4, biasc + 768, d_out, flag);
}

// Round 19
// 156.459 us; speedup vs baseline: 3.9286x; 1.0045x over previous
//
#include <hip/hip_runtime.h>

#define NN 10242

typedef short s8v __attribute__((ext_vector_type(8)));
typedef unsigned int u32x2 __attribute__((ext_vector_type(2)));
typedef float f32x4 __attribute__((ext_vector_type(4)));

static __device__ __forceinline__ float bf2f(unsigned short u) {
    unsigned int i = ((unsigned int)u) << 16;
    return __builtin_bit_cast(float, i);
}
static __device__ __forceinline__ float bfu32lo(unsigned int d) {
    return __builtin_bit_cast(float, d << 16);
}
static __device__ __forceinline__ float bfu32hi(unsigned int d) {
    return __builtin_bit_cast(float, d & 0xffff0000u);
}
static __device__ __forceinline__ unsigned short f2bf(float f) {
    unsigned int i = __builtin_bit_cast(unsigned int, f);
    unsigned int lsb = (i >> 16) & 1u;
    i += 0x7fffu + lsb;
    return (unsigned short)(i >> 16);
}
static __device__ __forceinline__ unsigned int cvtpk(float lo, float hi) {
    unsigned int r;
    asm("v_cvt_pk_bf16_f32 %0, %1, %2" : "=v"(r) : "v"(lo), "v"(hi));
    return r;
}
static __device__ __forceinline__ void gl_lds16(const unsigned short* g, unsigned short* l) {
    __builtin_amdgcn_global_load_lds(
        (const __attribute__((address_space(1))) unsigned int*)g,
        (__attribute__((address_space(3))) unsigned int*)l, 16, 0, 0);
}
template<int N> static __device__ __forceinline__ void waitv() {
    asm volatile("s_waitcnt vmcnt(%0)" :: "n"(N) : "memory");
    __builtin_amdgcn_sched_barrier(0);
}
static __device__ __forceinline__ void lgkm0() {
    asm volatile("s_waitcnt lgkmcnt(0)" ::: "memory");
    __builtin_amdgcn_sched_barrier(0);
}
static __device__ __forceinline__ int imin(int a, int b) { return a < b ? a : b; }

// in-wave dtype probe: lane r (0..63) checks row r of wgt; true => f32 source
static __device__ __forceinline__ bool probe_f32(const void* wgt, int lane) {
    const float* wf = (const float*)wgt;
    float s = wf[3 * lane] + wf[3 * lane + 1] + wf[3 * lane + 2];
    bool ok = (s == s) && (fabsf(s - 1.f) < 0.05f);
    unsigned long long m = __ballot(ok);
    return __popcll(m) >= 60;
}

// ---- canonicalizer (computes dtype flag per-block, no detect kernel) ----
struct Seg { const void* src; void* dst; int n; int nsrc; int mode; int K; int cout; int cpad; };
struct Tab { Seg s[16]; };

__global__ __launch_bounds__(256) void canon_k(Tab t, const void* __restrict__ wgt_raw) {
    __shared__ int fl;
    if (threadIdx.x < 64) {
        bool f = probe_f32(wgt_raw, threadIdx.x);
        if (threadIdx.x == 0) fl = f ? 1 : 0;
    }
    __syncthreads();
    const bool f32src = (fl != 0);
    const Seg sg = t.s[blockIdx.y];
    for (int i = blockIdx.x * 256 + threadIdx.x; i < sg.n; i += gridDim.x * 256) {
        if (sg.mode == 0) {
            unsigned short v = 0;
            if (i < sg.nsrc)
                v = f32src ? f2bf(((const float*)sg.src)[i])
                           : ((const unsigned short*)sg.src)[i];
            ((unsigned short*)sg.dst)[i] = v;
        } else if (sg.mode == 1) {
            float v = f32src ? ((const float*)sg.src)[i]
                             : bf2f(((const unsigned short*)sg.src)[i]);
            ((float*)sg.dst)[i] = v;
        } else if (sg.mode == 2) {
            const int row = i / 80, col = i - row * 80;
            unsigned short v = 0;
            if (col < 75) {
                const int j = row * 75 + col;
                v = f32src ? f2bf(((const float*)sg.src)[j])
                           : ((const unsigned short*)sg.src)[j];
            }
            ((unsigned short*)sg.dst)[i] = v;
        } else if (sg.mode == 3) {
            const int e = i & 7;
            const int r = i >> 3;
            const int c = r % sg.cpad;
            const int k8 = r / sg.cpad;
            unsigned short v = 0;
            if (c < sg.cout) {
                const int j = c * sg.K + k8 * 8 + e;
                v = f32src ? f2bf(((const float*)sg.src)[j])
                           : ((const unsigned short*)sg.src)[j];
            }
            ((unsigned short*)sg.dst)[i] = v;
        } else {
            const int row = i >> 2, col = i & 3;
            unsigned short v = 0;
            if (col < 3) {
                const int j = row * 3 + col;
                v = f32src ? f2bf(((const float*)sg.src)[j])
                           : ((const unsigned short*)sg.src)[j];
            }
            ((unsigned short*)sg.dst)[i] = v;
        }
    }
}

// ---- layer-1 conv (K=80, VALU) + fused per-block stats partials ----
template<int CIN4, int COUT, int CG, int NB>
__global__ __launch_bounds__(256) void conv1_k(
    const unsigned short* __restrict__ X4,
    const int* __restrict__ idx,
    const float* __restrict__ wgt,
    const unsigned short* __restrict__ W,
    const float* __restrict__ bias,
    float* __restrict__ Of,
    float* __restrict__ part)
{
    constexpr int K = 75;
    constexpr int KPAD = 80;
    __shared__ unsigned short agg[NB][KPAD];
    __shared__ float ls[256], ls2[256];
    const int tid = threadIdx.x;
    const int n0 = blockIdx.x * NB;

    for (int p = tid; p < NB * 25; p += 256) {
        const int r = p / 25;
        const int k = p - r * 25;
        const int n = n0 + r;
        if (n < NN) {
            const int base = n * 75 + k * 3;
            const int i0 = idx[base], i1 = idx[base + 1], i2 = idx[base + 2];
            const float w0 = wgt[base], w1 = wgt[base + 1], w2 = wgt[base + 2];
            const unsigned long long A = *(const unsigned long long*)(X4 + (size_t)i0 * 4);
            const unsigned long long B = *(const unsigned long long*)(X4 + (size_t)i1 * 4);
            const unsigned long long C = *(const unsigned long long*)(X4 + (size_t)i2 * 4);
            #pragma unroll
            for (int e = 0; e < 3; e++) {
                float v = w0 * bf2f((unsigned short)(A >> (16 * e))) +
                          w1 * bf2f((unsigned short)(B >> (16 * e))) +
                          w2 * bf2f((unsigned short)(C >> (16 * e)));
                agg[r][k * 3 + e] = f2bf(v);
            }
        } else {
            #pragma unroll
            for (int e = 0; e < 3; e++) agg[r][k * 3 + e] = 0;
        }
    }
    for (int p = tid; p < NB * (KPAD - K); p += 256) {
        const int r = p / (KPAD - K);
        agg[r][K + p - r * (KPAD - K)] = 0;
    }
    __syncthreads();

    constexpr int RG = 256 / CG;
    constexpr int RPT = NB / RG;
    const int c = tid % CG;
    const int rq = tid / CG;
    float acc[RPT] = {};
    const unsigned short* Wr = W + (size_t)c * KPAD;
    for (int j = 0; j < KPAD; j += 8) {
        s8v wv = *(const s8v*)(Wr + j);
        float wf[8];
        #pragma unroll
        for (int q = 0; q < 8; q++) wf[q] = bf2f((unsigned short)wv[q]);
        #pragma unroll
        for (int rr = 0; rr < RPT; rr++) {
            s8v av = *(const s8v*)(&agg[rq * RPT + rr][j]);
            #pragma unroll
            for (int q = 0; q < 8; q++)
                acc[rr] += wf[q] * bf2f((unsigned short)av[q]);
        }
    }
    const float bb = bias[c];
    float s = 0.f, s2 = 0.f;
    #pragma unroll
    for (int rr = 0; rr < RPT; rr++) {
        const int n = n0 + rq * RPT + rr;
        if (n < NN) {
            const float v = acc[rr] + bb;
            Of[(size_t)n * COUT + c] = v;
            s += v; s2 += v * v;
        }
    }
    ls[tid] = s; ls2[tid] = s2;
    __syncthreads();
    if (tid < COUT) {
        float a = 0.f, a2 = 0.f;
        #pragma unroll
        for (int g2 = 0; g2 < RG; g2++) {
            a  += ls[g2 * CG + tid];
            a2 += ls2[g2 * CG + tid];
        }
        part[(size_t)blockIdx.x * 2 * COUT + tid] = a;
        part[(size_t)blockIdx.x * 2 * COUT + COUT + tid] = a2;
    }
}

// ---- grouped DMA conv (CIN=64, ring-4, 2 slots/iteration, XOR-swizzled raw) ----
template<int COUTP, int COUT>
__global__ __launch_bounds__(256, 3) void convg_k(
    const unsigned short* __restrict__ X,
    const int* __restrict__ idx,
    const float* __restrict__ wgt,
    const unsigned short* __restrict__ Wt,   // [200][COUTP][8]
    const float* __restrict__ bias,
    float* __restrict__ pre,
    float* __restrict__ part)
{
    constexpr int CIN = 64;
    constexpr int NT = 2;
    constexpr int NFRAG = COUTP / 64;
    constexpr int Q = 2;
    constexpr int R = NT * NFRAG;
    __shared__ unsigned short raw[4 * 64 * CIN];
    __shared__ unsigned short agg[2][16][CIN + 8];
    __shared__ unsigned short iL[25 * 64];
    __shared__ float wL[25 * 48];
    const int tid = threadIdx.x;
    const int n0 = blockIdx.x * 16;

    for (int q = tid; q < 16 * 75; q += 256) {
        const int node = q / 75, f = q - node * 75;
        const int k = f / 3, v = f - k * 3;
        const int n = n0 + node;
        const bool ok = n < NN;
        const int g = ok ? (n * 75 + f) : 0;
        iL[k * 64 + node * 4 + v] = ok ? (unsigned short)idx[g] : 0;
        wL[k * 48 + node * 3 + v] = ok ? wgt[g] : 0.f;
    }
    for (int q = tid; q < 25 * 16; q += 256)
        iL[(q / 16) * 64 + (q - (q / 16) * 16) * 4 + 3] = 0;
    __syncthreads();

    const int wv = tid >> 6;
    const int lane = tid & 63;
    const int l15 = lane & 15;
    const int kg = lane >> 4;
    const int colbase = wv * NFRAG * 16;

    auto issue = [&](int sd) {
        const int base = (sd & 3) * (64 * CIN);
        #pragma unroll
        for (int jj = 0; jj < Q; jj++) {
            const int j = wv * Q + jj;
            const int row = j * 8 + (lane >> 3);
            const int p = lane & 7;
            const int ch = p ^ ((row >> 2) & 7);
            const int id = (int)iL[sd * 64 + row];
            gl_lds16(X + (size_t)id * CIN + ch * 8, &raw[base + j * 512]);
        }
    };
    auto loadB = [&](int sp, s8v* dst) {
        #pragma unroll
        for (int t = 0; t < NT; t++)
            #pragma unroll
            for (int j = 0; j < NFRAG; j++)
                dst[t * NFRAG + j] = *(const s8v*)(Wt +
                    ((size_t)(sp * 8 + t * 4 + kg) * COUTP + colbase + j * 16 + l15) * 8);
    };
    auto interp = [&](int s, int par) {
        const int sb = (s & 3) * (64 * CIN);
        const int node = tid >> 4;
        const int e4 = tid & 15;
        const float w0 = wL[s * 48 + node * 3 + 0];
        const float w1 = wL[s * 48 + node * 3 + 1];
        const float w2 = wL[s * 48 + node * 3 + 2];
        const int chunk = (e4 >> 1) ^ (node & 7);
        const int off = chunk * 8 + (e4 & 1) * 4;
        const int rb = sb + node * 4 * CIN + off;
        const u32x2 A = *(const u32x2*)&raw[rb + 0 * CIN];
        const u32x2 B = *(const u32x2*)&raw[rb + 1 * CIN];
        const u32x2 C = *(const u32x2*)&raw[rb + 2 * CIN];
        const float v0 = w0 * bfu32lo(A[0]) + w1 * bfu32lo(B[0]) + w2 * bfu32lo(C[0]);
        const float v1 = w0 * bfu32hi(A[0]) + w1 * bfu32hi(B[0]) + w2 * bfu32hi(C[0]);
        const float v2 = w0 * bfu32lo(A[1]) + w1 * bfu32lo(B[1]) + w2 * bfu32lo(C[1]);
        const float v3 = w0 * bfu32hi(A[1]) + w1 * bfu32hi(B[1]) + w2 * bfu32hi(C[1]);
        u32x2 o;
        o[0] = cvtpk(v0, v1);
        o[1] = cvtpk(v2, v3);
        *(u32x2*)&agg[par][node][e4 * 4] = o;
    };

    f32x4 acc[NFRAG] = {};
    s8v breg[2][2][R];

    issue(0); issue(1);
    loadB(0, breg[0][0]); loadB(1, breg[0][1]);
    issue(2); issue(3);

    #pragma unroll
    for (int g = 0; g < 12; g++) {
        const int s0 = 2 * g, s1 = 2 * g + 1;
        if (g < 11) { loadB(s0 + 2, breg[(g + 1) & 1][0]); loadB(s0 + 3, breg[(g + 1) & 1][1]); }
        else        { loadB(24, breg[(g + 1) & 1][0]); }
        if (g <= 10) waitv<2 * Q + 2 * R>(); else waitv<Q + R>();
        __builtin_amdgcn_s_barrier();
        interp(s0, 0);
        interp(s1, 1);
        lgkm0();
        __builtin_amdgcn_s_barrier();
        if (s0 + 4 < 25) issue(s0 + 4);
        if (s0 + 5 < 25) issue(s0 + 5);
        __builtin_amdgcn_sched_barrier(0);
        #pragma unroll
        for (int t = 0; t < NT; t++) {
            const s8v a0 = *(const s8v*)(&agg[0][l15][t * 32 + kg * 8]);
            #pragma unroll
            for (int j = 0; j < NFRAG; j++)
                acc[j] = __builtin_amdgcn_mfma_f32_16x16x32_bf16(
                    a0, breg[g & 1][0][t * NFRAG + j], acc[j], 0, 0, 0);
        }
        #pragma unroll
        for (int t = 0; t < NT; t++) {
            const s8v a1 = *(const s8v*)(&agg[1][l15][t * 32 + kg * 8]);
            #pragma unroll
            for (int j = 0; j < NFRAG; j++)
                acc[j] = __builtin_amdgcn_mfma_f32_16x16x32_bf16(
                    a1, breg[g & 1][1][t * NFRAG + j], acc[j], 0, 0, 0);
        }
    }
    waitv<0>();
    __builtin_amdgcn_s_barrier();
    interp(24, 0);
    lgkm0();
    __builtin_amdgcn_s_barrier();
    #pragma unroll
    for (int t = 0; t < NT; t++) {
        const s8v a = *(const s8v*)(&agg[0][l15][t * 32 + kg * 8]);
        #pragma unroll
        for (int j = 0; j < NFRAG; j++)
            acc[j] = __builtin_amdgcn_mfma_f32_16x16x32_bf16(
                a, breg[0][0][t * NFRAG + j], acc[j], 0, 0, 0);
    }

    #pragma unroll
    for (int j = 0; j < NFRAG; j++) {
        const int col = colbase + j * 16 + l15;
        float s = 0.f, s2 = 0.f;
        const float bb = bias[col];
        #pragma unroll
        for (int q = 0; q < 4; q++) {
            const int n = n0 + kg * 4 + q;
            if (n < NN) {
                const float v = acc[j][q] + bb;
                pre[(size_t)n * COUT + col] = v;
                s += v; s2 += v * v;
            }
        }
        s  += __shfl_xor(s, 16);  s  += __shfl_xor(s, 32);
        s2 += __shfl_xor(s2, 16); s2 += __shfl_xor(s2, 32);
        if (kg == 0) {
            part[(size_t)blockIdx.x * 2 * COUT + col] = s;
            part[(size_t)blockIdx.x * 2 * COUT + COUT + col] = s2;
        }
    }
}

// ---- layer-4 conv: CIN=128 as 50 half-slots of 64ch; ring-4, swizzled ----
__global__ __launch_bounds__(256, 3) void conv4_k(
    const unsigned short* __restrict__ X,    // [NN][128] bf16
    const int* __restrict__ idx,
    const float* __restrict__ wgt,           // canonical f32
    const void* __restrict__ wgt_raw,        // original input (for dtype probe)
    const unsigned short* __restrict__ Wt,   // [400][64][8]
    const float* __restrict__ bias,
    void* __restrict__ Ob)
{
    constexpr int COUTP = 64;
    constexpr int COUT = 36;
    constexpr int NT = 2;
    constexpr int Q = 2;
    constexpr int R = 2;
    __shared__ unsigned short raw[4 * 64 * 64];
    __shared__ unsigned short agg[2][16][72];
    __shared__ unsigned short iL[25 * 64];
    __shared__ float wL[25 * 48];
    __shared__ int fl;
    const int tid = threadIdx.x;
    const int n0 = blockIdx.x * 16;

    if (tid < 64) {
        bool f = probe_f32(wgt_raw, tid);
        if (tid == 0) fl = f ? 1 : 0;
    }
    for (int q = tid; q < 16 * 75; q += 256) {
        const int node = q / 75, f = q - node * 75;
        const int k = f / 3, v = f - k * 3;
        const int n = n0 + node;
        const bool ok = n < NN;
        const int g = ok ? (n * 75 + f) : 0;
        iL[k * 64 + node * 4 + v] = ok ? (unsigned short)idx[g] : 0;
        wL[k * 48 + node * 3 + v] = ok ? wgt[g] : 0.f;
    }
    for (int q = tid; q < 25 * 16; q += 256)
        iL[(q / 16) * 64 + (q - (q / 16) * 16) * 4 + 3] = 0;
    __syncthreads();

    const int wv = tid >> 6;
    const int lane = tid & 63;
    const int l15 = lane & 15;
    const int kg = lane >> 4;
    const int colbase = wv * 16;

    auto issue = [&](int u) {
        const int base = (u & 3) * (64 * 64);
        const int s = u >> 1, h = u & 1;
        #pragma unroll
        for (int jj = 0; jj < Q; jj++) {
            const int j = wv * Q + jj;
            const int row = j * 8 + (lane >> 3);
            const int p = lane & 7;
            const int ch = p ^ ((row >> 2) & 7);
            const int id = (int)iL[s * 64 + row];
            gl_lds16(X + (size_t)id * 128 + h * 64 + ch * 8, &raw[base + j * 512]);
        }
    };
    auto loadB = [&](int u, s8v* dst) {
        #pragma unroll
        for (int t = 0; t < NT; t++)
            dst[t] = *(const s8v*)(Wt +
                ((size_t)(u * 8 + t * 4 + kg) * COUTP + colbase + l15) * 8);
    };
    auto interp = [&](int u, int par) {
        const int sb = (u & 3) * (64 * 64);
        const int s = u >> 1;
        const int node = tid >> 4;
        const int e4 = tid & 15;
        const float w0 = wL[s * 48 + node * 3 + 0];
        const float w1 = wL[s * 48 + node * 3 + 1];
        const float w2 = wL[s * 48 + node * 3 + 2];
        const int chunk = (e4 >> 1) ^ (node & 7);
        const int off = chunk * 8 + (e4 & 1) * 4;
        const int rb = sb + node * 4 * 64 + off;
        const u32x2 A = *(const u32x2*)&raw[rb + 0 * 64];
        const u32x2 B = *(const u32x2*)&raw[rb + 1 * 64];
        const u32x2 C = *(const u32x2*)&raw[rb + 2 * 64];
        const float v0 = w0 * bfu32lo(A[0]) + w1 * bfu32lo(B[0]) + w2 * bfu32lo(C[0]);
        const float v1 = w0 * bfu32hi(A[0]) + w1 * bfu32hi(B[0]) + w2 * bfu32hi(C[0]);
        const float v2 = w0 * bfu32lo(A[1]) + w1 * bfu32lo(B[1]) + w2 * bfu32lo(C[1]);
        const float v3 = w0 * bfu32hi(A[1]) + w1 * bfu32hi(B[1]) + w2 * bfu32hi(C[1]);
        u32x2 o;
        o[0] = cvtpk(v0, v1);
        o[1] = cvtpk(v2, v3);
        *(u32x2*)&agg[par][node][e4 * 4] = o;
    };

    f32x4 acc = {};
    s8v breg[2][2][R];

    issue(0); issue(1);
    loadB(0, breg[0][0]); loadB(1, breg[0][1]);
    issue(2); issue(3);

    #pragma unroll
    for (int g = 0; g < 25; g++) {
        const int u0 = 2 * g, u1 = 2 * g + 1;
        if (g < 24) { loadB(u0 + 2, breg[(g + 1) & 1][0]); loadB(u0 + 3, breg[(g + 1) & 1][1]); }
        if (g <= 23) waitv<2 * Q + 2 * R>(); else waitv<0>();
        __builtin_amdgcn_s_barrier();
        interp(u0, 0);
        interp(u1, 1);
        lgkm0();
        __builtin_amdgcn_s_barrier();
        if (u0 + 4 < 50) issue(u0 + 4);
        if (u0 + 5 < 50) issue(u0 + 5);
        __builtin_amdgcn_sched_barrier(0);
        #pragma unroll
        for (int t = 0; t < NT; t++) {
            const s8v a0 = *(const s8v*)(&agg[0][l15][t * 32 + kg * 8]);
            acc = __builtin_amdgcn_mfma_f32_16x16x32_bf16(a0, breg[g & 1][0][t], acc, 0, 0, 0);
        }
        #pragma unroll
        for (int t = 0; t < NT; t++) {
            const s8v a1 = *(const s8v*)(&agg[1][l15][t * 32 + kg * 8]);
            acc = __builtin_amdgcn_mfma_f32_16x16x32_bf16(a1, breg[g & 1][1][t], acc, 0, 0, 0);
        }
    }

    const bool f32o = (fl != 0);
    const int col = colbase + l15;
    if (col < COUT) {
        const float bb = bias[col];
        #pragma unroll
        for (int q = 0; q < 4; q++) {
            const int n = n0 + kg * 4 + q;
            if (n < NN) {
                const float v = acc[q] + bb;
                if (f32o) ((float*)Ob)[(size_t)n * COUT + col] = v;
                else      ((unsigned short*)Ob)[(size_t)n * COUT + col] = f2bf(v);
            }
        }
    }
}

// ---- stats finalize: ONE block reduces NBLK partials -> scale/shift[2C] ----
template<int C, int NBLK>
__global__ __launch_bounds__(1024) void fin_k(
    const float* __restrict__ part,
    const float* __restrict__ gm,
    const float* __restrict__ bt,
    float* __restrict__ scsh)
{
    constexpr int RG = 1024 / C;
    __shared__ float ls[1024], ls2[1024];
    const int c = threadIdx.x % C;
    const int g = threadIdx.x / C;
    float s = 0.f, s2 = 0.f;
    for (int b = g; b < NBLK; b += RG) {
        s  += part[(size_t)b * 2 * C + c];
        s2 += part[(size_t)b * 2 * C + C + c];
    }
    ls[threadIdx.x] = s; ls2[threadIdx.x] = s2;
    __syncthreads();
    if (threadIdx.x < C) {
        float a = 0.f, a2 = 0.f;
        #pragma unroll
        for (int g2 = 0; g2 < RG; g2++) {
            a  += ls[g2 * C + threadIdx.x];
            a2 += ls2[g2 * C + threadIdx.x];
        }
        const float inv = 1.f / (float)NN;
        float mu = a * inv;
        float var = a2 * inv - mu * mu;
        float scale = gm[threadIdx.x] * rsqrtf(var + 1e-5f);
        scsh[threadIdx.x] = scale;
        scsh[C + threadIdx.x] = bt[threadIdx.x] - mu * scale;
    }
}

// ---- BN apply ----
template<int C>
__global__ __launch_bounds__(256) void bnap_k(
    const float* __restrict__ pre,
    const float* __restrict__ scsh,
    unsigned short* __restrict__ act)
{
    __shared__ float sc[C], sh[C];
    if (threadIdx.x < C) {
        sc[threadIdx.x] = scsh[threadIdx.x];
        sh[threadIdx.x] = scsh[C + threadIdx.x];
    }
    __syncthreads();
    constexpr int TOTAL4 = NN * C / 4;
    const int stride = gridDim.x * 256;
    for (int i = blockIdx.x * 256 + threadIdx.x; i < TOTAL4; i += stride) {
        const f32x4 v = *(const f32x4*)(pre + (size_t)i * 4);
        const int c0 = (i * 4) % C;
        u32x2 o;
        o[0] = cvtpk(fmaxf(v[0] * sc[c0]     + sh[c0],     0.f),
                     fmaxf(v[1] * sc[c0 + 1] + sh[c0 + 1], 0.f));
        o[1] = cvtpk(fmaxf(v[2] * sc[c0 + 2] + sh[c0 + 2], 0.f),
                     fmaxf(v[3] * sc[c0 + 3] + sh[c0 + 3], 0.f));
        *(u32x2*)(act + (size_t)i * 4) = o;
    }
}

extern "C" void kernel_launch(void* const* d_in, const int* in_sizes, int n_in,
                              void* d_out, int out_size, void* d_ws, size_t ws_size,
                              hipStream_t stream) {
    const void* x    = d_in[0];
    const int*  idx  = (const int*)d_in[1];
    const void* wgt  = d_in[2];
    const void* W1   = d_in[3];
    const void* b1   = d_in[4];
    const void* g1   = d_in[5];
    const void* be1  = d_in[6];
    const void* W2   = d_in[7];
    const void* b2   = d_in[8];
    const void* g2   = d_in[9];
    const void* be2  = d_in[10];
    const void* W3   = d_in[11];
    const void* b3   = d_in[12];
    const void* g3   = d_in[13];
    const void* be3  = d_in[14];
    const void* Wout = d_in[15];
    const void* bout = d_in[16];

    char* ws = (char*)d_ws;
    size_t off = 0;
    auto alloc = [&](size_t bytes) {
        off = (off + 255) & ~(size_t)255;
        size_t o = off; off += bytes; return o;
    };
    const size_t o_x4   = alloc((size_t)NN * 4 * 2);
    const size_t o_wgtc = alloc((size_t)NN * 75 * 4);
    const size_t o_W1c  = alloc(64 * 80 * 2);
    const size_t o_Wt2  = alloc((size_t)200 * 64 * 8 * 2);
    const size_t o_Wt3  = alloc((size_t)200 * 128 * 8 * 2);
    const size_t o_Wt4  = alloc((size_t)400 * 64 * 8 * 2);
    const size_t o_bias = alloc(1024 * 4);
    const size_t o_pre  = alloc((size_t)NN * 128 * 4);
    const size_t o_actA = alloc((size_t)NN * 128 * 2);
    const size_t o_actB = alloc((size_t)NN * 64 * 2);
    const size_t o_part = alloc((size_t)641 * 2 * 128 * 4);
    const size_t o_scsh = alloc(2 * 128 * 4);
    if (ws_size < off) return;

    unsigned short* x4  = (unsigned short*)(ws + o_x4);
    float* wgtc = (float*)(ws + o_wgtc);
    unsigned short* W1c = (unsigned short*)(ws + o_W1c);
    unsigned short* Wt2 = (unsigned short*)(ws + o_Wt2);
    unsigned short* Wt3 = (unsigned short*)(ws + o_Wt3);
    unsigned short* Wt4 = (unsigned short*)(ws + o_Wt4);
    float* biasc = (float*)(ws + o_bias);
    float* pre  = (float*)(ws + o_pre);
    unsigned short* actA = (unsigned short*)(ws + o_actA);
    unsigned short* actB = (unsigned short*)(ws + o_actB);
    float* part = (float*)(ws + o_part);
    float* scsh = (float*)(ws + o_scsh);

    Tab t;
    t.s[0]  = { x,    x4,   NN * 4,         NN * 3,  4, 0, 0, 0 };
    t.s[1]  = { wgt,  wgtc, NN * 75,        NN * 75, 1, 0, 0, 0 };
    t.s[2]  = { W1,   W1c,  64 * 80,        64 * 80, 2, 0, 0, 0 };
    t.s[3]  = { W2,   Wt2,  200 * 64 * 8,   0,       3, 1600, 64, 64 };
    t.s[4]  = { W3,   Wt3,  200 * 128 * 8,  0,       3, 1600, 128, 128 };
    t.s[5]  = { Wout, Wt4,  400 * 64 * 8,   0,       3, 3200, 36, 64 };
    t.s[6]  = { b1,   biasc + 0,   64, 64, 1, 0, 0, 0 };
    t.s[7]  = { g1,   biasc + 64,  64, 64, 1, 0, 0, 0 };
    t.s[8]  = { be1,  biasc + 128, 64, 64, 1, 0, 0, 0 };
    t.s[9]  = { b2,   biasc + 192, 64, 64, 1, 0, 0, 0 };
    t.s[10] = { g2,   biasc + 256, 64, 64, 1, 0, 0, 0 };
    t.s[11] = { be2,  biasc + 320, 64, 64, 1, 0, 0, 0 };
    t.s[12] = { b3,   biasc + 384, 128, 128, 1, 0, 0, 0 };
    t.s[13] = { g3,   biasc + 512, 128, 128, 1, 0, 0, 0 };
    t.s[14] = { be3,  biasc + 640, 128, 128, 1, 0, 0, 0 };
    t.s[15] = { bout, biasc + 768, 36, 36, 1, 0, 0, 0 };
    canon_k<<<dim3(192, 16), 256, 0, stream>>>(t, wgt);

    dim3 B(256);
    // layer 1: 3 -> 64 (VALU, vectorized gather, fused stats)
    conv1_k<4, 64, 64, 16><<<641, B, 0, stream>>>(x4, idx, wgtc, W1c, biasc + 0, pre, part);
    fin_k<64, 641><<<1, 1024, 0, stream>>>(part, biasc + 64, biasc + 128, scsh);
    bnap_k<64><<<256, B, 0, stream>>>(pre, scsh, actA);
    // layer 2: 64 -> 64 (grouped DMA, swizzled)
    convg_k<64, 64><<<641, B, 0, stream>>>(actA, idx, wgtc, Wt2, biasc + 192, pre, part);
    fin_k<64, 641><<<1, 1024, 0, stream>>>(part, biasc + 256, biasc + 320, scsh);
    bnap_k<64><<<256, B, 0, stream>>>(pre, scsh, actB);
    // layer 3: 64 -> 128 (grouped DMA, swizzled)
    convg_k<128, 128><<<641, B, 0, stream>>>(actB, idx, wgtc, Wt3, biasc + 384, pre, part);
    fin_k<128, 641><<<1, 1024, 0, stream>>>(part, biasc + 512, biasc + 640, scsh);
    bnap_k<128><<<256, B, 0, stream>>>(pre, scsh, actA);
    // layer 4: 128 -> 36 via 50 half-slots (ring-4, swizzled), direct to d_out
    conv4_k<<<641, B, 0, stream>>>(actA, idx, wgtc, wgt, Wt4, biasc + 768, d_out);
}